// Round 1
// 674.260 us; speedup vs baseline: 1.1422x; 1.1422x over previous
//
#include <hip/hip_runtime.h>
#include <hip/hip_bf16.h>
#include <math.h>

typedef __hip_bfloat16 bf16;
typedef __attribute__((ext_vector_type(8))) short short8;   // 8 x bf16 MFMA frag
typedef __attribute__((ext_vector_type(4))) float floatx4;  // 4 x f32 MFMA acc

// Problem constants: B=64, DIM=256, HID=512, NH=4, KD=16, D=64, 28x28, WH=7
#define BB    64
#define DIMC  256
#define HIDC  512
#define NHH   4
#define HH_   28
#define WW_   28
#define PP    784   // 28*28

__device__ __forceinline__ float toF(bf16 x) { return __bfloat162float(x); }
__device__ __forceinline__ unsigned short f2bits(float f) {
    union { bf16 h; unsigned short u; } cv; cv.h = __float2bfloat16(f); return cv.u;
}
__device__ __forceinline__ float bits2f(unsigned short u) {
    union { unsigned int u32; float f; } cv; cv.u32 = ((unsigned int)u) << 16; return cv.f;
}

// ---------------------------------------------------------------------------
// fp32 -> bf16 weight convert
// ---------------------------------------------------------------------------
__global__ __launch_bounds__(256) void cvt_f2b(
    const float* __restrict__ s, bf16* __restrict__ d, int n)
{
    int i = blockIdx.x * 256 + threadIdx.x;
    if (i < n) d[i] = __float2bfloat16(s[i]);
}

// ---------------------------------------------------------------------------
// fp32 NCHW [64][256][784] -> bf16 NHWC [64][784][256] (LDS 32x32 transpose)
// grid (25, 8, 64), block 256
// ---------------------------------------------------------------------------
__global__ __launch_bounds__(256) void tr_cvt(
    const float* __restrict__ in, bf16* __restrict__ out)
{
    __shared__ float t[32][33];
    int n  = blockIdx.z;
    int p0 = blockIdx.x * 32;
    int c0 = blockIdx.y * 32;
    int tx = threadIdx.x & 31;
    int ty = threadIdx.x >> 5;   // 0..7
#pragma unroll
    for (int e = 0; e < 4; e++) {
        int c = c0 + ty + e * 8;
        int p = p0 + tx;
        if (p < PP) t[ty + e * 8][tx] = in[((size_t)n * DIMC + c) * PP + p];
    }
    __syncthreads();
#pragma unroll
    for (int e = 0; e < 4; e++) {
        int p = p0 + ty + e * 8;
        int c = c0 + tx;
        if (p < PP) out[((size_t)n * PP + p) * DIMC + c] = __float2bfloat16(t[tx][ty + e * 8]);
    }
}

// ---------------------------------------------------------------------------
// Depthwise 3x3 conv + BN + residual (NCHW fp32) — ROUND-0 REWRITE.
// Old version: 9 bounds-guarded load+fma per pixel => 9 serialized vmcnt(0)
// stalls/pixel => 100 us (latency-bound, VALUBusy 14.6%, HBM 9.7%).
// New: 4 channels/block; zero-padded 30x30 LDS planes kill all bounds checks;
// stage via float4; compute 4-px row segments from LDS (18 unconditional
// ds_reads + 36 FMA per segment); float4 stores. Roofline ~12 us for 78 MB.
// grid (BB, DIMC/4), block 256. LDS 14.4 KB + weights.
// ---------------------------------------------------------------------------
#define CPB 4
__global__ __launch_bounds__(256) void dw3x3_kernel(
    const float* __restrict__ in, const float* __restrict__ w,
    const float* __restrict__ s, const float* __restrict__ b,
    float* __restrict__ out)
{
    __shared__ float t[CPB][30 * 30];        // padded planes, zero halo
    __shared__ float wS[CPB * 9 + 2 * CPB];  // 9 weights + scale + bias per ch

    int n   = blockIdx.x;
    int c0  = blockIdx.y * CPB;
    int tid = threadIdx.x;
    const float* ip = in  + ((size_t)n * DIMC + c0) * PP;
    float*       op = out + ((size_t)n * DIMC + c0) * PP;

    // weights/scale/bias -> LDS
    if (tid < CPB * 9)                wS[tid] = w[c0 * 9 + tid];
    else if (tid < CPB * 10)          wS[tid] = s[c0 + tid - CPB * 9];
    else if (tid < CPB * 11)          wS[tid] = b[c0 + tid - CPB * 10];

    // zero-fill padded planes (halo must be 0; interior overwritten below)
    for (int i = tid; i < CPB * 900; i += 256) ((float*)t)[i] = 0.f;
    __syncthreads();

    // stage: CPB*196 float4 tasks; each row of 28 = 7 aligned float4
    for (int idx = tid; idx < CPB * 196; idx += 256) {
        int ch  = idx / 196;
        int rm  = idx - ch * 196;
        int row = rm / 7, seg = rm - row * 7;
        float4 v = *(const float4*)&ip[ch * PP + row * 28 + seg * 4];
        float* dst = &t[ch][(row + 1) * 30 + seg * 4 + 1];
        dst[0] = v.x; dst[1] = v.y; dst[2] = v.z; dst[3] = v.w;
    }
    __syncthreads();

    // compute: 4-px segments; padded window rows row..row+2, cols x0..x0+5
    for (int idx = tid; idx < CPB * 196; idx += 256) {
        int ch  = idx / 196;
        int rm  = idx - ch * 196;
        int row = rm / 7, seg = rm - row * 7;
        int x0  = seg * 4;
        float w9[9];
#pragma unroll
        for (int i = 0; i < 9; i++) w9[i] = wS[ch * 9 + i];
        float sc = wS[CPB * 9 + ch], bb = wS[CPB * 10 + ch];

        float acc[4] = {0.f, 0.f, 0.f, 0.f};
        float ctr[4];
        const float* base = &t[ch][row * 30 + x0];
#pragma unroll
        for (int i = 0; i < 3; i++) {
            float r[6];
#pragma unroll
            for (int k = 0; k < 6; k++) r[k] = base[i * 30 + k];
            if (i == 1) { ctr[0] = r[1]; ctr[1] = r[2]; ctr[2] = r[3]; ctr[3] = r[4]; }
#pragma unroll
            for (int j = 0; j < 3; j++)
#pragma unroll
                for (int q = 0; q < 4; q++)
                    acc[q] += w9[i * 3 + j] * r[j + q];
        }
        float4 o;
        o.x = ctr[0] + acc[0] * sc + bb;
        o.y = ctr[1] + acc[1] * sc + bb;
        o.z = ctr[2] + acc[2] * sc + bb;
        o.w = ctr[3] + acc[3] * sc + bb;
        *(float4*)&op[ch * PP + row * 28 + x0] = o;
    }
}

// ---------------------------------------------------------------------------
// Per-head depthwise 5x5 + BN on q channels, NHWC bf16 in/out. (proven r8)
// ---------------------------------------------------------------------------
__global__ __launch_bounds__(256) void dws5x5_nhwc(
    const bf16* __restrict__ qkv,   // [64][784][384]
    const float* __restrict__ w,    // [64][25]  (hk-major)
    const float* __restrict__ s, const float* __restrict__ b,
    bf16* __restrict__ qout)        // [64][784][64]
{
    int n  = blockIdx.y;
    int p  = blockIdx.x * 4 + (threadIdx.x >> 6);
    int hk = threadIdx.x & 63;
    int hh = hk >> 4, kc = hk & 15;
    int cin = hh * 96 + kc;
    int h = p / 28, x = p % 28;
    float w25[25];
#pragma unroll
    for (int i = 0; i < 25; i++) w25[i] = w[hk * 25 + i];
    float acc = 0.f;
#pragma unroll
    for (int i = 0; i < 5; i++) {
        int h2 = h + i - 2;
        if (h2 < 0 || h2 >= HH_) continue;
#pragma unroll
        for (int j = 0; j < 5; j++) {
            int x2 = x + j - 2;
            if (x2 < 0 || x2 >= WW_) continue;
            acc += w25[i * 5 + j] * toF(qkv[((size_t)n * PP + h2 * 28 + x2) * 384 + cin]);
        }
    }
    qout[((size_t)n * PP + p) * 64 + hk] = __float2bfloat16(acc * s[hk] + b[hk]);
}

// ---------------------------------------------------------------------------
// 1x1 conv as bf16 MFMA GEMM — EXACT r8 version (proven at 791 us total).
// Tile 64(co) x 112(p), K-step 32, 4 waves; uint4 staging, pitch-40 LDS.
// OUTMODE: 0 = bf16 NHWC; 1 = fp32 NCHW; 2 = both.   grid (7, M/64, 64)
// ---------------------------------------------------------------------------
template <bool RELU, bool RES, int OUTMODE>
__global__ __launch_bounds__(256) void gemm_mfma(
    const bf16* __restrict__ Wb,    // [M][K] bf16
    const bf16* __restrict__ X,     // [64][784][K] bf16 NHWC
    const float* __restrict__ S, const float* __restrict__ Bb,
    const float* __restrict__ res,  // [64][M][784] fp32 NCHW (if RES)
    float* __restrict__ outF,       // fp32 NCHW (OUTMODE 1/2)
    bf16*  __restrict__ outB,       // bf16 NHWC (OUTMODE 0/2)
    int M, int K)
{
    int n    = blockIdx.z;
    int co0  = blockIdx.y * 64;
    int p0   = blockIdx.x * 112;
    int tid  = threadIdx.x;
    int wv   = tid >> 6;
    int ln   = tid & 63;
    int l15  = ln & 15;
    int quad = ln >> 4;

    __shared__ __align__(16) unsigned short Blds[112 * 40];  // [pp][kk], pitch 40

    floatx4 acc[7];
#pragma unroll
    for (int t = 0; t < 7; t++) acc[t] = (floatx4){0.f, 0.f, 0.f, 0.f};

    const bf16* Arow = Wb + (size_t)(co0 + wv * 16 + l15) * K + quad * 8;
    const unsigned short* Xb = (const unsigned short*)X + ((size_t)n * PP + p0) * K;

    int pp_a = tid >> 2, G_a = tid & 3;                 // pp_a in [0,64)
    int idx_b = tid + 256;
    int pp_b = idx_b >> 2, G_b = idx_b & 3;             // pp_b in [64,128), valid < 112

    for (int k0 = 0; k0 < K; k0 += 32) {
        {
            uint4 v = *(const uint4*)(Xb + (size_t)pp_a * K + k0 + G_a * 8);
            *(uint4*)&Blds[pp_a * 40 + G_a * 8] = v;
        }
        if (idx_b < 448) {
            uint4 v = *(const uint4*)(Xb + (size_t)pp_b * K + k0 + G_b * 8);
            *(uint4*)&Blds[pp_b * 40 + G_b * 8] = v;
        }
        short8 afrag = *(const short8*)(Arow + k0);
        __syncthreads();
#pragma unroll
        for (int t = 0; t < 7; t++) {
            short8 bfrag = *(const short8*)&Blds[(t * 16 + l15) * 40 + quad * 8];
            acc[t] = __builtin_amdgcn_mfma_f32_16x16x32_bf16(afrag, bfrag, acc[t], 0, 0, 0);
        }
        __syncthreads();
    }

    int cobase = co0 + wv * 16 + quad * 4;
    float s4[4], b4[4];
#pragma unroll
    for (int r = 0; r < 4; r++) { s4[r] = S[cobase + r]; b4[r] = Bb[cobase + r]; }

#pragma unroll
    for (int t = 0; t < 7; t++) {
        int p = p0 + t * 16 + l15;   // always < 784
        float y[4];
#pragma unroll
        for (int r = 0; r < 4; r++) {
            y[r] = acc[t][r] * s4[r] + b4[r];
            if (RELU) y[r] = fmaxf(y[r], 0.f);
            if (RES) y[r] += res[((size_t)n * M + cobase + r) * PP + p];
        }
        if (OUTMODE == 1 || OUTMODE == 2) {
#pragma unroll
            for (int r = 0; r < 4; r++)
                outF[((size_t)n * M + cobase + r) * PP + p] = y[r];
        }
        if (OUTMODE == 0 || OUTMODE == 2) {
            union { unsigned short h4[4]; uint2 u; } pk;
#pragma unroll
            for (int r = 0; r < 4; r++) pk.h4[r] = f2bits(y[r]);
            *(uint2*)((unsigned short*)outB + ((size_t)n * PP + p) * M + cobase) = pk.u;
        }
    }
}

// ---------------------------------------------------------------------------
// 7x7 window attention, NHWC bf16 I/O. Block per (n, head, win-row, col-pair).
// grid (8, 4, 64). Covers 2 windows: lp = r*14 + c, global p = pbase+r*28+c.
// ROUND-10 CHANGE (LDS-throughput fix): register-blocked inner loops.
//  - q/k in LDS as [lp][kc] pitch 18 (bank stride 9, coprime 32); S loop reads
//    packed u32 (2 kc per read): 16 LDS reads per S entry instead of 32.
//  - v in LDS pitch 64 u16; PV thread owns (lp, 8 channels): per ki ONE
//    ds_read_b128 (8 ch) + one b32 srow read feeds 16 FLOP (was 2 reads/4 FLOP).
//  - sL pitch 50 (2-way bank aliasing = free). LDS total 39.1 KB -> 4 blocks/CU.
// ---------------------------------------------------------------------------
__global__ __launch_bounds__(256) void attn_kernel(
    const bf16*  __restrict__ Q,       // [64][784][64] NHWC (hk = hh*16+kc)
    const bf16*  __restrict__ KV,      // [64][784][384] NHWC
    const float* __restrict__ pos,     // [4][49][49]
    bf16* __restrict__ O)              // [64][784][256] NHWC (c = hh*64+d)
{
    int wjp = blockIdx.x & 1, wi = blockIdx.x >> 1;
    int hh  = blockIdx.y, n = blockIdx.z;
    int tid = threadIdx.x;
    int pbase = wi * 7 * 28 + wjp * 14;

    __shared__ __align__(16) unsigned short qL[98 * 18];   // [lp][kc] pitch 18
    __shared__ __align__(16) unsigned short kL[98 * 18];
    __shared__ __align__(16) unsigned short vL[98 * 64];   // [lp][d] pitch 64
    __shared__ float sL[98 * 50];                          // [w*49+qi][ki] pitch 50

    const unsigned short* KVu = (const unsigned short*)KV;
    const unsigned short* Qu  = (const unsigned short*)Q;

    // ---- load q, k as u32 pairs: 784 tasks = 98 lp x 8 kc-pairs ----
    for (int idx = tid; idx < 784; idx += 256) {
        int lp = idx >> 3, e = idx & 7;
        int p  = pbase + (lp / 14) * 28 + lp % 14;
        unsigned int qv = *(const unsigned int*)&Qu[((size_t)n * PP + p) * 64 + hh * 16 + e * 2];
        unsigned int kv = *(const unsigned int*)&KVu[((size_t)n * PP + p) * 384 + hh * 96 + 16 + e * 2];
        *(unsigned int*)&qL[lp * 18 + e * 2] = qv;
        *(unsigned int*)&kL[lp * 18 + e * 2] = kv;
    }
    // ---- load v as u32 pairs: 3136 tasks = 98 lp x 32 ch-pairs ----
    for (int idx = tid; idx < 3136; idx += 256) {
        int lp = idx >> 5, d2 = idx & 31;
        int p = pbase + (lp / 14) * 28 + lp % 14;
        unsigned int vv = *(const unsigned int*)&KVu[((size_t)n * PP + p) * 384 + hh * 96 + 32 + d2 * 2];
        *(unsigned int*)&vL[lp * 64 + d2 * 2] = vv;
    }
    __syncthreads();

    // ---- S = 0.25*q.k + pos  (2 windows x 49 x 49) ----
    for (int idx = tid; idx < 4802; idx += 256) {
        int w  = idx / 2401;
        int rm = idx - w * 2401;
        int qi = rm / 49, ki = rm - qi * 49;
        int lpq = (qi / 7) * 14 + w * 7 + qi % 7;
        int lpk = (ki / 7) * 14 + w * 7 + ki % 7;
        float acc = 0.f;
#pragma unroll
        for (int e = 0; e < 8; e++) {
            unsigned int qw = *(const unsigned int*)&qL[lpq * 18 + e * 2];
            unsigned int kw = *(const unsigned int*)&kL[lpk * 18 + e * 2];
            acc += bits2f((unsigned short)(qw & 0xFFFF)) * bits2f((unsigned short)(kw & 0xFFFF));
            acc += bits2f((unsigned short)(qw >> 16))    * bits2f((unsigned short)(kw >> 16));
        }
        sL[(w * 49 + qi) * 50 + ki] = acc * 0.25f + pos[(hh * 49 + qi) * 49 + ki];
    }
    __syncthreads();

    // ---- softmax (one thread per row; 98 rows) ----
    if (tid < 98) {
        float* row = &sL[tid * 50];
        float m = row[0];
        for (int ki = 1; ki < 49; ki++) m = fmaxf(m, row[ki]);
        float sum = 0.f;
        for (int ki = 0; ki < 49; ki++) {
            float e = __expf(row[ki] - m);
            row[ki] = e;
            sum += e;
        }
        float inv = 1.f / sum;
        for (int ki = 0; ki < 49; ki++) row[ki] *= inv;
    }
    __syncthreads();

    // ---- O = relu(attn @ V): 784 tasks = 98 lp x 8 channel-groups of 8 ----
    unsigned short* Ou = (unsigned short*)O;
    for (int idx = tid; idx < 784; idx += 256) {
        int lp = idx >> 3, g = idx & 7;
        int r = lp / 14, c = lp % 14;
        int w = c / 7, cc = c - w * 7;
        int qi = r * 7 + cc;
        const float* srow = &sL[(w * 49 + qi) * 50];
        float a[8] = {0.f, 0.f, 0.f, 0.f, 0.f, 0.f, 0.f, 0.f};
#pragma unroll
        for (int ki = 0; ki < 49; ki++) {
            int lpk = (ki / 7) * 14 + w * 7 + ki % 7;
            union { uint4 q; unsigned short h[8]; } v8;
            v8.q = *(const uint4*)&vL[lpk * 64 + g * 8];
            float sv = srow[ki];
#pragma unroll
            for (int j = 0; j < 8; j++) a[j] += sv * bits2f(v8.h[j]);
        }
        int p = pbase + r * 28 + c;
        union { uint4 q; unsigned short h[8]; } o8;
#pragma unroll
        for (int j = 0; j < 8; j++) o8.h[j] = f2bits(fmaxf(a[j], 0.f));
        *(uint4*)&Ou[((size_t)n * PP + p) * 256 + hh * 64 + g * 8] = o8.q;
    }
}

// ---------------------------------------------------------------------------
extern "C" void kernel_launch(void* const* d_in, const int* in_sizes, int n_in,
                              void* d_out, int out_size, void* d_ws, size_t ws_size,
                              hipStream_t stream)
{
    const float* x0     = (const float*)d_in[0];
    const float* dw0_w  = (const float*)d_in[1];
    const float* dw0_s  = (const float*)d_in[2];
    const float* dw0_b  = (const float*)d_in[3];
    const float* dw1_w  = (const float*)d_in[4];
    const float* dw1_s  = (const float*)d_in[5];
    const float* dw1_b  = (const float*)d_in[6];
    const float* f0w1   = (const float*)d_in[7];
    const float* f0s1   = (const float*)d_in[8];
    const float* f0b1   = (const float*)d_in[9];
    const float* f0w2   = (const float*)d_in[10];
    const float* f0s2   = (const float*)d_in[11];
    const float* f0b2   = (const float*)d_in[12];
    const float* f1w1   = (const float*)d_in[13];
    const float* f1s1   = (const float*)d_in[14];
    const float* f1b1   = (const float*)d_in[15];
    const float* f1w2   = (const float*)d_in[16];
    const float* f1s2   = (const float*)d_in[17];
    const float* f1b2   = (const float*)d_in[18];
    const float* qkv_w  = (const float*)d_in[19];
    const float* qkv_s  = (const float*)d_in[20];
    const float* qkv_b  = (const float*)d_in[21];
    const float* dws_w  = (const float*)d_in[22];
    const float* dws_s  = (const float*)d_in[23];
    const float* dws_b  = (const float*)d_in[24];
    const float* proj_w = (const float*)d_in[25];
    const float* proj_s = (const float*)d_in[26];
    const float* proj_b = (const float*)d_in[27];
    const float* pos    = (const float*)d_in[28];

    // -------- workspace (aliased, same proven r8 scheme) --------
    const size_t NXB = (size_t)BB * DIMC * PP * 4;    // 51,380,224 B
    char* base  = (char*)d_ws;
    float* X1   = (float*)base;
    bf16*  Hb   = (bf16*)(base + NXB);
    bf16*  Qb   = Hb;                                  // alias, disjoint in time
    char*  C_   = base + 2 * NXB;
    bf16*  QKVb = (bf16*)C_;
    float* X2   = (float*)C_;                          // alias, disjoint in time
    bf16*  X1b  = (bf16*)(base + 3 * NXB);             // 25.7 MB
    bf16*  Wc   = (bf16*)(base + 3 * NXB + NXB / 2);
    bf16*  Ob   = (bf16*)d_out;
    float* outp = (float*)d_out;

    bf16* Wf0w1 = Wc;                  // [512][256]
    bf16* Wf0w2 = Wf0w1 + 131072;      // [256][512]
    bf16* Wf1w1 = Wf0w2 + 131072;      // [512][256]
    bf16* Wf1w2 = Wf1w1 + 131072;      // [256][512]
    bf16* Wqkv  = Wf1w2 + 131072;      // [384][256]
    bf16* Wproj = Wqkv + 98304;        // [256][256]

    dim3 blk(256);

    // 0) weights fp32 -> bf16
    cvt_f2b<<<512, blk, 0, stream>>>(f0w1, Wf0w1, 131072);
    cvt_f2b<<<512, blk, 0, stream>>>(f0w2, Wf0w2, 131072);
    cvt_f2b<<<512, blk, 0, stream>>>(f1w1, Wf1w1, 131072);
    cvt_f2b<<<512, blk, 0, stream>>>(f1w2, Wf1w2, 131072);
    cvt_f2b<<<384, blk, 0, stream>>>(qkv_w, Wqkv, 98304);
    cvt_f2b<<<256, blk, 0, stream>>>(proj_w, Wproj, 65536);

    // 1) x = x + dw0(x); mirror to NHWC bf16
    dw3x3_kernel<<<dim3(BB, DIMC / CPB), blk, 0, stream>>>(x0, dw0_w, dw0_s, dw0_b, X1);
    tr_cvt<<<dim3(25, 8, BB), blk, 0, stream>>>(X1, X1b);

    // 2-3) ffn0 (second GEMM refreshes both X1 fp32 and X1b NHWC)
    gemm_mfma<true, false, 0><<<dim3(7, HIDC / 64, BB), blk, 0, stream>>>(
        Wf0w1, X1b, f0s1, f0b1, nullptr, nullptr, Hb, HIDC, DIMC);
    gemm_mfma<false, true, 2><<<dim3(7, DIMC / 64, BB), blk, 0, stream>>>(
        Wf0w2, Hb, f0s2, f0b2, X1, X1, X1b, DIMC, HIDC);

    // 4-7) attention
    gemm_mfma<false, false, 0><<<dim3(7, 384 / 64, BB), blk, 0, stream>>>(
        Wqkv, X1b, qkv_s, qkv_b, nullptr, nullptr, QKVb, 384, DIMC);
    dws5x5_nhwc<<<dim3(196, BB), blk, 0, stream>>>(QKVb, dws_w, dws_s, dws_b, Qb);
    attn_kernel<<<dim3(8, NHH, BB), blk, 0, stream>>>(Qb, QKVb, pos, Ob);
    gemm_mfma<false, true, 1><<<dim3(7, DIMC / 64, BB), blk, 0, stream>>>(
        Wproj, Ob, proj_s, proj_b, X1, X1, nullptr, DIMC, DIMC);

    // 8) x = x + dw1(x)  (QKVb dead -> X2); mirror to NHWC bf16 (reuse X1b)
    dw3x3_kernel<<<dim3(BB, DIMC / CPB), blk, 0, stream>>>(X1, dw1_w, dw1_s, dw1_b, X2);
    tr_cvt<<<dim3(25, 8, BB), blk, 0, stream>>>(X2, X1b);

    // 9-10) ffn1, final fp32 NCHW to d_out
    gemm_mfma<true, false, 0><<<dim3(7, HIDC / 64, BB), blk, 0, stream>>>(
        Wf1w1, X1b, f1s1, f1b1, nullptr, nullptr, Hb, HIDC, DIMC);
    gemm_mfma<false, true, 1><<<dim3(7, DIMC / 64, BB), blk, 0, stream>>>(
        Wf1w2, Hb, f1s2, f1b2, X2, outp, nullptr, DIMC, HIDC);
}

// Round 3
// 630.264 us; speedup vs baseline: 1.2219x; 1.0698x over previous
//
#include <hip/hip_runtime.h>
#include <hip/hip_bf16.h>
#include <math.h>

typedef __hip_bfloat16 bf16;
typedef __attribute__((ext_vector_type(8))) short short8;   // 8 x bf16 MFMA frag
typedef __attribute__((ext_vector_type(4))) float floatx4;  // 4 x f32 MFMA acc

// Problem constants: B=64, DIM=256, HID=512, NH=4, KD=16, D=64, 28x28, WH=7
#define BB    64
#define DIMC  256
#define HIDC  512
#define NHH   4
#define HH_   28
#define WW_   28
#define PP    784   // 28*28

__device__ __forceinline__ float toF(bf16 x) { return __bfloat162float(x); }
__device__ __forceinline__ unsigned short f2bits(float f) {
    union { bf16 h; unsigned short u; } cv; cv.h = __float2bfloat16(f); return cv.u;
}
__device__ __forceinline__ float bits2f(unsigned short u) {
    union { unsigned int u32; float f; } cv; cv.u32 = ((unsigned int)u) << 16; return cv.f;
}

// ---------------------------------------------------------------------------
// fp32 -> bf16 weight convert
// ---------------------------------------------------------------------------
__global__ __launch_bounds__(256) void cvt_f2b(
    const float* __restrict__ s, bf16* __restrict__ d, int n)
{
    int i = blockIdx.x * 256 + threadIdx.x;
    if (i < n) d[i] = __float2bfloat16(s[i]);
}

// ---------------------------------------------------------------------------
// fp32 NCHW [64][256][784] -> bf16 NHWC [64][784][256] (LDS 32x32 transpose)
// grid (25, 8, 64), block 256
// ---------------------------------------------------------------------------
__global__ __launch_bounds__(256) void tr_cvt(
    const float* __restrict__ in, bf16* __restrict__ out)
{
    __shared__ float t[32][33];
    int n  = blockIdx.z;
    int p0 = blockIdx.x * 32;
    int c0 = blockIdx.y * 32;
    int tx = threadIdx.x & 31;
    int ty = threadIdx.x >> 5;   // 0..7
#pragma unroll
    for (int e = 0; e < 4; e++) {
        int c = c0 + ty + e * 8;
        int p = p0 + tx;
        if (p < PP) t[ty + e * 8][tx] = in[((size_t)n * DIMC + c) * PP + p];
    }
    __syncthreads();
#pragma unroll
    for (int e = 0; e < 4; e++) {
        int p = p0 + ty + e * 8;
        int c = c0 + tx;
        if (p < PP) out[((size_t)n * PP + p) * DIMC + c] = __float2bfloat16(t[tx][ty + e * 8]);
    }
}

// ---------------------------------------------------------------------------
// Depthwise 3x3 conv + BN + residual (NCHW fp32) — round-0 LDS version.
// ---------------------------------------------------------------------------
#define CPB 4
__global__ __launch_bounds__(256) void dw3x3_kernel(
    const float* __restrict__ in, const float* __restrict__ w,
    const float* __restrict__ s, const float* __restrict__ b,
    float* __restrict__ out)
{
    __shared__ float t[CPB][30 * 30];        // padded planes, zero halo
    __shared__ float wS[CPB * 9 + 2 * CPB];  // 9 weights + scale + bias per ch

    int n   = blockIdx.x;
    int c0  = blockIdx.y * CPB;
    int tid = threadIdx.x;
    const float* ip = in  + ((size_t)n * DIMC + c0) * PP;
    float*       op = out + ((size_t)n * DIMC + c0) * PP;

    // weights/scale/bias -> LDS
    if (tid < CPB * 9)                wS[tid] = w[c0 * 9 + tid];
    else if (tid < CPB * 10)          wS[tid] = s[c0 + tid - CPB * 9];
    else if (tid < CPB * 11)          wS[tid] = b[c0 + tid - CPB * 10];

    // zero-fill padded planes (halo must be 0; interior overwritten below)
    for (int i = tid; i < CPB * 900; i += 256) ((float*)t)[i] = 0.f;
    __syncthreads();

    // stage: CPB*196 float4 tasks; each row of 28 = 7 aligned float4
    for (int idx = tid; idx < CPB * 196; idx += 256) {
        int ch  = idx / 196;
        int rm  = idx - ch * 196;
        int row = rm / 7, seg = rm - row * 7;
        float4 v = *(const float4*)&ip[ch * PP + row * 28 + seg * 4];
        float* dst = &t[ch][(row + 1) * 30 + seg * 4 + 1];
        dst[0] = v.x; dst[1] = v.y; dst[2] = v.z; dst[3] = v.w;
    }
    __syncthreads();

    // compute: 4-px segments; padded window rows row..row+2, cols x0..x0+5
    for (int idx = tid; idx < CPB * 196; idx += 256) {
        int ch  = idx / 196;
        int rm  = idx - ch * 196;
        int row = rm / 7, seg = rm - row * 7;
        int x0  = seg * 4;
        float w9[9];
#pragma unroll
        for (int i = 0; i < 9; i++) w9[i] = wS[ch * 9 + i];
        float sc = wS[CPB * 9 + ch], bb = wS[CPB * 10 + ch];

        float acc[4] = {0.f, 0.f, 0.f, 0.f};
        float ctr[4];
        const float* base = &t[ch][row * 30 + x0];
#pragma unroll
        for (int i = 0; i < 3; i++) {
            float r[6];
#pragma unroll
            for (int k = 0; k < 6; k++) r[k] = base[i * 30 + k];
            if (i == 1) { ctr[0] = r[1]; ctr[1] = r[2]; ctr[2] = r[3]; ctr[3] = r[4]; }
#pragma unroll
            for (int j = 0; j < 3; j++)
#pragma unroll
                for (int q = 0; q < 4; q++)
                    acc[q] += w9[i * 3 + j] * r[j + q];
        }
        float4 o;
        o.x = ctr[0] + acc[0] * sc + bb;
        o.y = ctr[1] + acc[1] * sc + bb;
        o.z = ctr[2] + acc[2] * sc + bb;
        o.w = ctr[3] + acc[3] * sc + bb;
        *(float4*)&op[ch * PP + row * 28 + x0] = o;
    }
}

// ---------------------------------------------------------------------------
// Per-head depthwise 5x5 + BN on q channels, NHWC bf16 in/out. (proven r8)
// ---------------------------------------------------------------------------
__global__ __launch_bounds__(256) void dws5x5_nhwc(
    const bf16* __restrict__ qkv,   // [64][784][384]
    const float* __restrict__ w,    // [64][25]  (hk-major)
    const float* __restrict__ s, const float* __restrict__ b,
    bf16* __restrict__ qout)        // [64][784][64]
{
    int n  = blockIdx.y;
    int p  = blockIdx.x * 4 + (threadIdx.x >> 6);
    int hk = threadIdx.x & 63;
    int hh = hk >> 4, kc = hk & 15;
    int cin = hh * 96 + kc;
    int h = p / 28, x = p % 28;
    float w25[25];
#pragma unroll
    for (int i = 0; i < 25; i++) w25[i] = w[hk * 25 + i];
    float acc = 0.f;
#pragma unroll
    for (int i = 0; i < 5; i++) {
        int h2 = h + i - 2;
        if (h2 < 0 || h2 >= HH_) continue;
#pragma unroll
        for (int j = 0; j < 5; j++) {
            int x2 = x + j - 2;
            if (x2 < 0 || x2 >= WW_) continue;
            acc += w25[i * 5 + j] * toF(qkv[((size_t)n * PP + h2 * 28 + x2) * 384 + cin]);
        }
    }
    qout[((size_t)n * PP + p) * 64 + hk] = __float2bfloat16(acc * s[hk] + b[hk]);
}

// ---------------------------------------------------------------------------
// 1x1 conv as bf16 MFMA GEMM — EXACT r8 version (proven at 791 us total).
// Tile 64(co) x 112(p), K-step 32, 4 waves; uint4 staging, pitch-40 LDS.
// OUTMODE: 0 = bf16 NHWC; 1 = fp32 NCHW; 2 = both.   grid (7, M/64, 64)
// ---------------------------------------------------------------------------
template <bool RELU, bool RES, int OUTMODE>
__global__ __launch_bounds__(256) void gemm_mfma(
    const bf16* __restrict__ Wb,    // [M][K] bf16
    const bf16* __restrict__ X,     // [64][784][K] bf16 NHWC
    const float* __restrict__ S, const float* __restrict__ Bb,
    const float* __restrict__ res,  // [64][M][784] fp32 NCHW (if RES)
    float* __restrict__ outF,       // fp32 NCHW (OUTMODE 1/2)
    bf16*  __restrict__ outB,       // bf16 NHWC (OUTMODE 0/2)
    int M, int K)
{
    int n    = blockIdx.z;
    int co0  = blockIdx.y * 64;
    int p0   = blockIdx.x * 112;
    int tid  = threadIdx.x;
    int wv   = tid >> 6;
    int ln   = tid & 63;
    int l15  = ln & 15;
    int quad = ln >> 4;

    __shared__ __align__(16) unsigned short Blds[112 * 40];  // [pp][kk], pitch 40

    floatx4 acc[7];
#pragma unroll
    for (int t = 0; t < 7; t++) acc[t] = (floatx4){0.f, 0.f, 0.f, 0.f};

    const bf16* Arow = Wb + (size_t)(co0 + wv * 16 + l15) * K + quad * 8;
    const unsigned short* Xb = (const unsigned short*)X + ((size_t)n * PP + p0) * K;

    int pp_a = tid >> 2, G_a = tid & 3;                 // pp_a in [0,64)
    int idx_b = tid + 256;
    int pp_b = idx_b >> 2, G_b = idx_b & 3;             // pp_b in [64,128), valid < 112

    for (int k0 = 0; k0 < K; k0 += 32) {
        {
            uint4 v = *(const uint4*)(Xb + (size_t)pp_a * K + k0 + G_a * 8);
            *(uint4*)&Blds[pp_a * 40 + G_a * 8] = v;
        }
        if (idx_b < 448) {
            uint4 v = *(const uint4*)(Xb + (size_t)pp_b * K + k0 + G_b * 8);
            *(uint4*)&Blds[pp_b * 40 + G_b * 8] = v;
        }
        short8 afrag = *(const short8*)(Arow + k0);
        __syncthreads();
#pragma unroll
        for (int t = 0; t < 7; t++) {
            short8 bfrag = *(const short8*)&Blds[(t * 16 + l15) * 40 + quad * 8];
            acc[t] = __builtin_amdgcn_mfma_f32_16x16x32_bf16(afrag, bfrag, acc[t], 0, 0, 0);
        }
        __syncthreads();
    }

    int cobase = co0 + wv * 16 + quad * 4;
    float s4[4], b4[4];
#pragma unroll
    for (int r = 0; r < 4; r++) { s4[r] = S[cobase + r]; b4[r] = Bb[cobase + r]; }

#pragma unroll
    for (int t = 0; t < 7; t++) {
        int p = p0 + t * 16 + l15;   // always < 784
        float y[4];
#pragma unroll
        for (int r = 0; r < 4; r++) {
            y[r] = acc[t][r] * s4[r] + b4[r];
            if (RELU) y[r] = fmaxf(y[r], 0.f);
            if (RES) y[r] += res[((size_t)n * M + cobase + r) * PP + p];
        }
        if (OUTMODE == 1 || OUTMODE == 2) {
#pragma unroll
            for (int r = 0; r < 4; r++)
                outF[((size_t)n * M + cobase + r) * PP + p] = y[r];
        }
        if (OUTMODE == 0 || OUTMODE == 2) {
            union { unsigned short h4[4]; uint2 u; } pk;
#pragma unroll
            for (int r = 0; r < 4; r++) pk.h4[r] = f2bits(y[r]);
            *(uint2*)((unsigned short*)outB + ((size_t)n * PP + p) * M + cobase) = pk.u;
        }
    }
}

// ---------------------------------------------------------------------------
// 7x7 window attention — ROUND-1 MFMA REWRITE (resubmitted; round-2 bench was
// an infra timeout, no signal).
// Old: all-VALU S/PV loops (VALUBusy 79%, MfmaUtil 0, 88.5 us).
// New: S^T = mfma(K,Q) so a lane-group holds a full score column (fixed q,
// all ki) -> softmax = 15 in-reg fmax + 2 shfl_xor; P packed to bf16 in regs,
// written once to LDS (aliases dead q/k buffers); O = mfma(P, V^T).
// 24 MFMAs/wave; kernel becomes staging-bound.
// LDS: qS/kS 2x[64][40] u16 (proven pitch) | vT 2x[64][72] u16 | posL [64][50]
// f32; pS aliases qS+kS after a barrier. Total 51.7 KB -> 3 blocks/CU.
// grid (8, 4, 64), block 256.
// ---------------------------------------------------------------------------
__global__ __launch_bounds__(256) void attn_kernel(
    const bf16*  __restrict__ Q,       // [64][784][64] NHWC (hk = hh*16+kc)
    const bf16*  __restrict__ KV,      // [64][784][384] NHWC
    const float* __restrict__ pos,     // [4][49][49]
    bf16* __restrict__ O)              // [64][784][256] NHWC (c = hh*64+d)
{
    int wjp = blockIdx.x & 1, wi = blockIdx.x >> 1;
    int hh  = blockIdx.y, n = blockIdx.z;
    int tid = threadIdx.x;
    int pbase = wi * 7 * 28 + wjp * 14;

    __shared__ __align__(16) char smem[51712];
    unsigned short* qS = (unsigned short*)smem;              // [2][64][40]
    unsigned short* kS = qS + 2 * 64 * 40;                   // [2][64][40]
    unsigned short* pS = (unsigned short*)smem;              // alias: [2][64][72]
    unsigned short* vT = (unsigned short*)(smem + 20480);    // [2][64][72]
    float*          posL = (float*)(smem + 20480 + 18432);   // [64][50]

    const unsigned short* Qu  = (const unsigned short*)Q;
    const unsigned short* KVu = (const unsigned short*)KV;

    // ---- stage q/k: 2 bufs x 2 windows x 64 rows x 5 halves (zero-padded) ----
    for (int idx = tid; idx < 1280; idx += 256) {
        int which = idx >= 640 ? 1 : 0;
        int t2 = idx - which * 640;
        int w = t2 / 320, rm = t2 - w * 320;
        int row = rm / 5, half = rm - row * 5;
        uint4 v = make_uint4(0u, 0u, 0u, 0u);
        if (row < 49 && half < 2) {
            int p = pbase + (row / 7) * 28 + w * 7 + (row % 7);
            const unsigned short* src = which
                ? &KVu[((size_t)n * PP + p) * 384 + hh * 96 + 16 + half * 8]
                : &Qu[((size_t)n * PP + p) * 64 + hh * 16 + half * 8];
            v = *(const uint4*)src;
        }
        *(uint4*)((which ? kS : qS) + (w * 64 + row) * 40 + half * 8) = v;
    }
    // ---- stage V transposed: vT[w][d][ki], zero rows for ki >= 49 ----
    for (int idx = tid; idx < 1024; idx += 256) {
        int w = idx >> 9, rm = idx & 511;
        int ki = rm >> 3, dq = rm & 7;
        union { uint4 q; unsigned short h[8]; } v;
        v.q = make_uint4(0u, 0u, 0u, 0u);
        if (ki < 49) {
            int p = pbase + (ki / 7) * 28 + w * 7 + (ki % 7);
            v.q = *(const uint4*)&KVu[((size_t)n * PP + p) * 384 + hh * 96 + 32 + dq * 8];
        }
#pragma unroll
        for (int j = 0; j < 8; j++)
            vT[(w * 64 + dq * 8 + j) * 72 + ki] = v.h[j];
    }
    // ---- stage pos [64][50], zero-padded ----
    for (int idx = tid; idx < 3200; idx += 256) {
        int r = idx / 50, c = idx - r * 50;
        posL[idx] = (r < 49 && c < 49) ? pos[((size_t)hh * 49 + r) * 49 + c] : 0.f;
    }
    __syncthreads();

    int wv = tid >> 6, ln = tid & 63, l15 = ln & 15, quad = ln >> 4;

    // ---- S^T via MFMA + in-register softmax; hold packed bf16 P ----
    uint2 pk[2][4];
#pragma unroll
    for (int w = 0; w < 2; w++) {
        short8 qf = *(const short8*)&qS[(w * 64 + wv * 16 + l15) * 40 + quad * 8];
        floatx4 a4[4];
#pragma unroll
        for (int kt = 0; kt < 4; kt++) {
            short8 kf = *(const short8*)&kS[(w * 64 + kt * 16 + l15) * 40 + quad * 8];
            a4[kt] = __builtin_amdgcn_mfma_f32_16x16x32_bf16(
                kf, qf, (floatx4){0.f, 0.f, 0.f, 0.f}, 0, 0, 0);
        }
        int q = wv * 16 + l15;
        float sv[16];
        float m = -1e30f;
#pragma unroll
        for (int kt = 0; kt < 4; kt++) {
#pragma unroll
            for (int r = 0; r < 4; r++) {
                int ki = kt * 16 + quad * 4 + r;
                float sc = (ki < 49)
                    ? a4[kt][r] * 0.25f + posL[q * 50 + ki]
                    : -1e30f;
                sv[kt * 4 + r] = sc;
                m = fmaxf(m, sc);
            }
        }
        m = fmaxf(m, __shfl_xor(m, 16));
        m = fmaxf(m, __shfl_xor(m, 32));
        float sum = 0.f;
#pragma unroll
        for (int i = 0; i < 16; i++) { sv[i] = __expf(sv[i] - m); sum += sv[i]; }
        sum += __shfl_xor(sum, 16);
        sum += __shfl_xor(sum, 32);
        float inv = 1.f / sum;
#pragma unroll
        for (int kt = 0; kt < 4; kt++) {
            union { uint2 u; unsigned short h[4]; } pku;
#pragma unroll
            for (int r = 0; r < 4; r++) pku.h[r] = f2bits(sv[kt * 4 + r] * inv);
            pk[w][kt] = pku.u;
        }
    }
    __syncthreads();   // all qS/kS MFMA reads done before aliasing writes

    {
        int q = wv * 16 + l15;
#pragma unroll
        for (int w = 0; w < 2; w++)
#pragma unroll
            for (int kt = 0; kt < 4; kt++)
                *(uint2*)&pS[(w * 64 + q) * 72 + kt * 16 + quad * 4] = pk[w][kt];
    }
    __syncthreads();

    // ---- O = relu(P @ V) via MFMA ----
    unsigned short* Ou = (unsigned short*)O;
#pragma unroll
    for (int w = 0; w < 2; w++) {
        short8 af0 = *(const short8*)&pS[(w * 64 + wv * 16 + l15) * 72 + quad * 8];
        short8 af1 = *(const short8*)&pS[(w * 64 + wv * 16 + l15) * 72 + 32 + quad * 8];
#pragma unroll
        for (int dt = 0; dt < 4; dt++) {
            floatx4 oacc = (floatx4){0.f, 0.f, 0.f, 0.f};
            short8 vf0 = *(const short8*)&vT[(w * 64 + dt * 16 + l15) * 72 + quad * 8];
            short8 vf1 = *(const short8*)&vT[(w * 64 + dt * 16 + l15) * 72 + 32 + quad * 8];
            oacc = __builtin_amdgcn_mfma_f32_16x16x32_bf16(af0, vf0, oacc, 0, 0, 0);
            oacc = __builtin_amdgcn_mfma_f32_16x16x32_bf16(af1, vf1, oacc, 0, 0, 0);
#pragma unroll
            for (int r = 0; r < 4; r++) {
                int q = wv * 16 + quad * 4 + r;
                if (q < 49) {
                    int p = pbase + (q / 7) * 28 + w * 7 + (q % 7);
                    Ou[((size_t)n * PP + p) * 256 + hh * 64 + dt * 16 + l15] =
                        f2bits(fmaxf(oacc[r], 0.f));
                }
            }
        }
    }
}

// ---------------------------------------------------------------------------
extern "C" void kernel_launch(void* const* d_in, const int* in_sizes, int n_in,
                              void* d_out, int out_size, void* d_ws, size_t ws_size,
                              hipStream_t stream)
{
    const float* x0     = (const float*)d_in[0];
    const float* dw0_w  = (const float*)d_in[1];
    const float* dw0_s  = (const float*)d_in[2];
    const float* dw0_b  = (const float*)d_in[3];
    const float* dw1_w  = (const float*)d_in[4];
    const float* dw1_s  = (const float*)d_in[5];
    const float* dw1_b  = (const float*)d_in[6];
    const float* f0w1   = (const float*)d_in[7];
    const float* f0s1   = (const float*)d_in[8];
    const float* f0b1   = (const float*)d_in[9];
    const float* f0w2   = (const float*)d_in[10];
    const float* f0s2   = (const float*)d_in[11];
    const float* f0b2   = (const float*)d_in[12];
    const float* f1w1   = (const float*)d_in[13];
    const float* f1s1   = (const float*)d_in[14];
    const float* f1b1   = (const float*)d_in[15];
    const float* f1w2   = (const float*)d_in[16];
    const float* f1s2   = (const float*)d_in[17];
    const float* f1b2   = (const float*)d_in[18];
    const float* qkv_w  = (const float*)d_in[19];
    const float* qkv_s  = (const float*)d_in[20];
    const float* qkv_b  = (const float*)d_in[21];
    const float* dws_w  = (const float*)d_in[22];
    const float* dws_s  = (const float*)d_in[23];
    const float* dws_b  = (const float*)d_in[24];
    const float* proj_w = (const float*)d_in[25];
    const float* proj_s = (const float*)d_in[26];
    const float* proj_b = (const float*)d_in[27];
    const float* pos    = (const float*)d_in[28];

    // -------- workspace (aliased, same proven r8 scheme) --------
    const size_t NXB = (size_t)BB * DIMC * PP * 4;    // 51,380,224 B
    char* base  = (char*)d_ws;
    float* X1   = (float*)base;
    bf16*  Hb   = (bf16*)(base + NXB);
    bf16*  Qb   = Hb;                                  // alias, disjoint in time
    char*  C_   = base + 2 * NXB;
    bf16*  QKVb = (bf16*)C_;
    float* X2   = (float*)C_;                          // alias, disjoint in time
    bf16*  X1b  = (bf16*)(base + 3 * NXB);             // 25.7 MB
    bf16*  Wc   = (bf16*)(base + 3 * NXB + NXB / 2);
    bf16*  Ob   = (bf16*)d_out;
    float* outp = (float*)d_out;

    bf16* Wf0w1 = Wc;                  // [512][256]
    bf16* Wf0w2 = Wf0w1 + 131072;      // [256][512]
    bf16* Wf1w1 = Wf0w2 + 131072;      // [512][256]
    bf16* Wf1w2 = Wf1w1 + 131072;      // [256][512]
    bf16* Wqkv  = Wf1w2 + 131072;      // [384][256]
    bf16* Wproj = Wqkv + 98304;        // [256][256]

    dim3 blk(256);

    // 0) weights fp32 -> bf16
    cvt_f2b<<<512, blk, 0, stream>>>(f0w1, Wf0w1, 131072);
    cvt_f2b<<<512, blk, 0, stream>>>(f0w2, Wf0w2, 131072);
    cvt_f2b<<<512, blk, 0, stream>>>(f1w1, Wf1w1, 131072);
    cvt_f2b<<<512, blk, 0, stream>>>(f1w2, Wf1w2, 131072);
    cvt_f2b<<<384, blk, 0, stream>>>(qkv_w, Wqkv, 98304);
    cvt_f2b<<<256, blk, 0, stream>>>(proj_w, Wproj, 65536);

    // 1) x = x + dw0(x); mirror to NHWC bf16
    dw3x3_kernel<<<dim3(BB, DIMC / CPB), blk, 0, stream>>>(x0, dw0_w, dw0_s, dw0_b, X1);
    tr_cvt<<<dim3(25, 8, BB), blk, 0, stream>>>(X1, X1b);

    // 2-3) ffn0 (second GEMM refreshes both X1 fp32 and X1b NHWC)
    gemm_mfma<true, false, 0><<<dim3(7, HIDC / 64, BB), blk, 0, stream>>>(
        Wf0w1, X1b, f0s1, f0b1, nullptr, nullptr, Hb, HIDC, DIMC);
    gemm_mfma<false, true, 2><<<dim3(7, DIMC / 64, BB), blk, 0, stream>>>(
        Wf0w2, Hb, f0s2, f0b2, X1, X1, X1b, DIMC, HIDC);

    // 4-7) attention
    gemm_mfma<false, false, 0><<<dim3(7, 384 / 64, BB), blk, 0, stream>>>(
        Wqkv, X1b, qkv_s, qkv_b, nullptr, nullptr, QKVb, 384, DIMC);
    dws5x5_nhwc<<<dim3(196, BB), blk, 0, stream>>>(QKVb, dws_w, dws_s, dws_b, Qb);
    attn_kernel<<<dim3(8, NHH, BB), blk, 0, stream>>>(Qb, QKVb, pos, Ob);
    gemm_mfma<false, true, 1><<<dim3(7, DIMC / 64, BB), blk, 0, stream>>>(
        Wproj, Ob, proj_s, proj_b, X1, X1, nullptr, DIMC, DIMC);

    // 8) x = x + dw1(x)  (QKVb dead -> X2); mirror to NHWC bf16 (reuse X1b)
    dw3x3_kernel<<<dim3(BB, DIMC / CPB), blk, 0, stream>>>(X1, dw1_w, dw1_s, dw1_b, X2);
    tr_cvt<<<dim3(25, 8, BB), blk, 0, stream>>>(X2, X1b);

    // 9-10) ffn1, final fp32 NCHW to d_out
    gemm_mfma<true, false, 0><<<dim3(7, HIDC / 64, BB), blk, 0, stream>>>(
        Wf1w1, X1b, f1s1, f1b1, nullptr, nullptr, Hb, HIDC, DIMC);
    gemm_mfma<false, true, 1><<<dim3(7, DIMC / 64, BB), blk, 0, stream>>>(
        Wf1w2, Hb, f1s2, f1b2, X2, outp, nullptr, DIMC, HIDC);
}

// Round 4
// 589.371 us; speedup vs baseline: 1.3067x; 1.0694x over previous
//
#include <hip/hip_runtime.h>
#include <hip/hip_bf16.h>
#include <math.h>

typedef __hip_bfloat16 bf16;
typedef __attribute__((ext_vector_type(8))) short short8;   // 8 x bf16 MFMA frag
typedef __attribute__((ext_vector_type(4))) float floatx4;  // 4 x f32 MFMA acc

// Problem constants: B=64, DIM=256, HID=512, NH=4, KD=16, D=64, 28x28, WH=7
#define BB    64
#define DIMC  256
#define HIDC  512
#define NHH   4
#define HH_   28
#define WW_   28
#define PP    784   // 28*28

__device__ __forceinline__ float toF(bf16 x) { return __bfloat162float(x); }
__device__ __forceinline__ unsigned short f2bits(float f) {
    union { bf16 h; unsigned short u; } cv; cv.h = __float2bfloat16(f); return cv.u;
}
__device__ __forceinline__ float bits2f(unsigned short u) {
    union { unsigned int u32; float f; } cv; cv.u32 = ((unsigned int)u) << 16; return cv.f;
}

// ---------------------------------------------------------------------------
// fp32 -> bf16 weight convert — single merged launch for all 6 weight arrays
// grid 2688 x 256 covers 688128 elements.
// ---------------------------------------------------------------------------
__global__ __launch_bounds__(256) void cvt_all(
    const float* __restrict__ s0, bf16* __restrict__ d0,   // 131072
    const float* __restrict__ s1, bf16* __restrict__ d1,   // 131072
    const float* __restrict__ s2, bf16* __restrict__ d2,   // 131072
    const float* __restrict__ s3, bf16* __restrict__ d3,   // 131072
    const float* __restrict__ s4, bf16* __restrict__ d4,   // 98304
    const float* __restrict__ s5, bf16* __restrict__ d5)   // 65536
{
    int i = blockIdx.x * 256 + threadIdx.x;
    if (i < 131072)                d0[i]          = __float2bfloat16(s0[i]);
    else if (i < 262144)           d1[i - 131072] = __float2bfloat16(s1[i - 131072]);
    else if (i < 393216)           d2[i - 262144] = __float2bfloat16(s2[i - 262144]);
    else if (i < 524288)           d3[i - 393216] = __float2bfloat16(s3[i - 393216]);
    else if (i < 622592)           d4[i - 524288] = __float2bfloat16(s4[i - 524288]);
    else if (i < 688128)           d5[i - 622592] = __float2bfloat16(s5[i - 622592]);
}

// ---------------------------------------------------------------------------
// fp32 NCHW [64][256][784] -> bf16 NHWC [64][784][256] (LDS 32x32 transpose)
// grid (25, 8, 64), block 256
// ---------------------------------------------------------------------------
__global__ __launch_bounds__(256) void tr_cvt(
    const float* __restrict__ in, bf16* __restrict__ out)
{
    __shared__ float t[32][33];
    int n  = blockIdx.z;
    int p0 = blockIdx.x * 32;
    int c0 = blockIdx.y * 32;
    int tx = threadIdx.x & 31;
    int ty = threadIdx.x >> 5;   // 0..7
#pragma unroll
    for (int e = 0; e < 4; e++) {
        int c = c0 + ty + e * 8;
        int p = p0 + tx;
        if (p < PP) t[ty + e * 8][tx] = in[((size_t)n * DIMC + c) * PP + p];
    }
    __syncthreads();
#pragma unroll
    for (int e = 0; e < 4; e++) {
        int p = p0 + ty + e * 8;
        int c = c0 + tx;
        if (p < PP) out[((size_t)n * PP + p) * DIMC + c] = __float2bfloat16(t[tx][ty + e * 8]);
    }
}

// ---------------------------------------------------------------------------
// Depthwise 3x3 conv + BN + residual (NCHW fp32) — round-0 LDS version.
// ---------------------------------------------------------------------------
#define CPB 4
__global__ __launch_bounds__(256) void dw3x3_kernel(
    const float* __restrict__ in, const float* __restrict__ w,
    const float* __restrict__ s, const float* __restrict__ b,
    float* __restrict__ out)
{
    __shared__ float t[CPB][30 * 30];        // padded planes, zero halo
    __shared__ float wS[CPB * 9 + 2 * CPB];  // 9 weights + scale + bias per ch

    int n   = blockIdx.x;
    int c0  = blockIdx.y * CPB;
    int tid = threadIdx.x;
    const float* ip = in  + ((size_t)n * DIMC + c0) * PP;
    float*       op = out + ((size_t)n * DIMC + c0) * PP;

    // weights/scale/bias -> LDS
    if (tid < CPB * 9)                wS[tid] = w[c0 * 9 + tid];
    else if (tid < CPB * 10)          wS[tid] = s[c0 + tid - CPB * 9];
    else if (tid < CPB * 11)          wS[tid] = b[c0 + tid - CPB * 10];

    // zero-fill padded planes (halo must be 0; interior overwritten below)
    for (int i = tid; i < CPB * 900; i += 256) ((float*)t)[i] = 0.f;
    __syncthreads();

    // stage: CPB*196 float4 tasks; each row of 28 = 7 aligned float4
    for (int idx = tid; idx < CPB * 196; idx += 256) {
        int ch  = idx / 196;
        int rm  = idx - ch * 196;
        int row = rm / 7, seg = rm - row * 7;
        float4 v = *(const float4*)&ip[ch * PP + row * 28 + seg * 4];
        float* dst = &t[ch][(row + 1) * 30 + seg * 4 + 1];
        dst[0] = v.x; dst[1] = v.y; dst[2] = v.z; dst[3] = v.w;
    }
    __syncthreads();

    // compute: 4-px segments; padded window rows row..row+2, cols x0..x0+5
    for (int idx = tid; idx < CPB * 196; idx += 256) {
        int ch  = idx / 196;
        int rm  = idx - ch * 196;
        int row = rm / 7, seg = rm - row * 7;
        int x0  = seg * 4;
        float w9[9];
#pragma unroll
        for (int i = 0; i < 9; i++) w9[i] = wS[ch * 9 + i];
        float sc = wS[CPB * 9 + ch], bb = wS[CPB * 10 + ch];

        float acc[4] = {0.f, 0.f, 0.f, 0.f};
        float ctr[4];
        const float* base = &t[ch][row * 30 + x0];
#pragma unroll
        for (int i = 0; i < 3; i++) {
            float r[6];
#pragma unroll
            for (int k = 0; k < 6; k++) r[k] = base[i * 30 + k];
            if (i == 1) { ctr[0] = r[1]; ctr[1] = r[2]; ctr[2] = r[3]; ctr[3] = r[4]; }
#pragma unroll
            for (int j = 0; j < 3; j++)
#pragma unroll
                for (int q = 0; q < 4; q++)
                    acc[q] += w9[i * 3 + j] * r[j + q];
        }
        float4 o;
        o.x = ctr[0] + acc[0] * sc + bb;
        o.y = ctr[1] + acc[1] * sc + bb;
        o.z = ctr[2] + acc[2] * sc + bb;
        o.w = ctr[3] + acc[3] * sc + bb;
        *(float4*)&op[ch * PP + row * 28 + x0] = o;
    }
}

// ---------------------------------------------------------------------------
// Per-head depthwise 5x5 + BN on q channels, NHWC bf16 in/out. (proven r8)
// ---------------------------------------------------------------------------
__global__ __launch_bounds__(256) void dws5x5_nhwc(
    const bf16* __restrict__ qkv,   // [64][784][384]
    const float* __restrict__ w,    // [64][25]  (hk-major)
    const float* __restrict__ s, const float* __restrict__ b,
    bf16* __restrict__ qout)        // [64][784][64]
{
    int n  = blockIdx.y;
    int p  = blockIdx.x * 4 + (threadIdx.x >> 6);
    int hk = threadIdx.x & 63;
    int hh = hk >> 4, kc = hk & 15;
    int cin = hh * 96 + kc;
    int h = p / 28, x = p % 28;
    float w25[25];
#pragma unroll
    for (int i = 0; i < 25; i++) w25[i] = w[hk * 25 + i];
    float acc = 0.f;
#pragma unroll
    for (int i = 0; i < 5; i++) {
        int h2 = h + i - 2;
        if (h2 < 0 || h2 >= HH_) continue;
#pragma unroll
        for (int j = 0; j < 5; j++) {
            int x2 = x + j - 2;
            if (x2 < 0 || x2 >= WW_) continue;
            acc += w25[i * 5 + j] * toF(qkv[((size_t)n * PP + h2 * 28 + x2) * 384 + cin]);
        }
    }
    qout[((size_t)n * PP + p) * 64 + hk] = __float2bfloat16(acc * s[hk] + b[hk]);
}

// ---------------------------------------------------------------------------
// 1x1 conv as bf16 MFMA GEMM — ROUND-3: 2-phase double-buffered pipeline.
// Old: load -> LDS -> barrier -> MFMA -> barrier exposed full global-load
// latency every K-step (w2 GEMM: 3.34 TB/s = 53% of achievable, MfmaUtil 7.6%).
// New: prefetch tile t+1 (X tile + A frag) into REGISTERS before the MFMA
// phase on LDS[t&1]; consume at the LDS[t^1] write after the barrier. Load
// latency hides under 7x(ds_read_b128+MFMA). LDS 2x8.96 KB.
// Tile 64(co) x 112(p), K-step 32, 4 waves.
// OUTMODE: 0 = bf16 NHWC; 1 = fp32 NCHW; 2 = both.   grid (7, M/64, 64)
// ---------------------------------------------------------------------------
template <bool RELU, bool RES, int OUTMODE>
__global__ __launch_bounds__(256) void gemm_mfma(
    const bf16* __restrict__ Wb,    // [M][K] bf16
    const bf16* __restrict__ X,     // [64][784][K] bf16 NHWC
    const float* __restrict__ S, const float* __restrict__ Bb,
    const float* __restrict__ res,  // [64][M][784] fp32 NCHW (if RES)
    float* __restrict__ outF,       // fp32 NCHW (OUTMODE 1/2)
    bf16*  __restrict__ outB,       // bf16 NHWC (OUTMODE 0/2)
    int M, int K)
{
    int n    = blockIdx.z;
    int co0  = blockIdx.y * 64;
    int p0   = blockIdx.x * 112;
    int tid  = threadIdx.x;
    int wv   = tid >> 6;
    int ln   = tid & 63;
    int l15  = ln & 15;
    int quad = ln >> 4;

    __shared__ __align__(16) unsigned short Blds[2][112 * 40];  // dbuf, pitch 40

    floatx4 acc[7];
#pragma unroll
    for (int t = 0; t < 7; t++) acc[t] = (floatx4){0.f, 0.f, 0.f, 0.f};

    const bf16* Arow = Wb + (size_t)(co0 + wv * 16 + l15) * K + quad * 8;
    const unsigned short* Xb = (const unsigned short*)X + ((size_t)n * PP + p0) * K;

    int pp_a = tid >> 2, G_a = tid & 3;                 // pp_a in [0,64)
    int idx_b = tid + 256;
    int pp_b = idx_b >> 2, G_b = idx_b & 3;             // pp_b in [64,128), valid < 112
    bool has_b = idx_b < 448;

    const unsigned short* pa = Xb + (size_t)pp_a * K + G_a * 8;
    const unsigned short* pb = Xb + (size_t)pp_b * K + G_b * 8;

    // prologue: stage tile 0 into LDS[0]; A-frag 0 into regs
    {
        uint4 va = *(const uint4*)pa;
        *(uint4*)&Blds[0][pp_a * 40 + G_a * 8] = va;
        if (has_b) {
            uint4 vb = *(const uint4*)pb;
            *(uint4*)&Blds[0][pp_b * 40 + G_b * 8] = vb;
        }
    }
    short8 af = *(const short8*)Arow;
    __syncthreads();

    int NT = K >> 5;
    for (int t = 0; t < NT; t++) {
        int cur = t & 1;
        // ---- issue prefetch of tile t+1 (held in regs; vmcnt waited at write) ----
        uint4 nva = make_uint4(0u, 0u, 0u, 0u), nvb = make_uint4(0u, 0u, 0u, 0u);
        short8 naf = af;
        if (t + 1 < NT) {
            nva = *(const uint4*)(pa + (t + 1) * 32);
            if (has_b) nvb = *(const uint4*)(pb + (t + 1) * 32);
            naf = *(const short8*)(Arow + (t + 1) * 32);
        }
        // ---- compute on LDS[cur] (not blocked by the loads above) ----
#pragma unroll
        for (int tt = 0; tt < 7; tt++) {
            short8 bfrag = *(const short8*)&Blds[cur][(tt * 16 + l15) * 40 + quad * 8];
            acc[tt] = __builtin_amdgcn_mfma_f32_16x16x32_bf16(af, bfrag, acc[tt], 0, 0, 0);
        }
        if (t + 1 < NT) {
            __syncthreads();   // iter t-1 readers of LDS[cur^1] are done
            *(uint4*)&Blds[cur ^ 1][pp_a * 40 + G_a * 8] = nva;
            if (has_b) *(uint4*)&Blds[cur ^ 1][pp_b * 40 + G_b * 8] = nvb;
            af = naf;
            __syncthreads();   // LDS[cur^1] ready for iter t+1
        }
    }

    int cobase = co0 + wv * 16 + quad * 4;
    float s4[4], b4[4];
#pragma unroll
    for (int r = 0; r < 4; r++) { s4[r] = S[cobase + r]; b4[r] = Bb[cobase + r]; }

#pragma unroll
    for (int t = 0; t < 7; t++) {
        int p = p0 + t * 16 + l15;   // always < 784
        float y[4];
#pragma unroll
        for (int r = 0; r < 4; r++) {
            y[r] = acc[t][r] * s4[r] + b4[r];
            if (RELU) y[r] = fmaxf(y[r], 0.f);
            if (RES) y[r] += res[((size_t)n * M + cobase + r) * PP + p];
        }
        if (OUTMODE == 1 || OUTMODE == 2) {
#pragma unroll
            for (int r = 0; r < 4; r++)
                outF[((size_t)n * M + cobase + r) * PP + p] = y[r];
        }
        if (OUTMODE == 0 || OUTMODE == 2) {
            union { unsigned short h4[4]; uint2 u; } pk;
#pragma unroll
            for (int r = 0; r < 4; r++) pk.h4[r] = f2bits(y[r]);
            *(uint2*)((unsigned short*)outB + ((size_t)n * PP + p) * M + cobase) = pk.u;
        }
    }
}

// ---------------------------------------------------------------------------
// 7x7 window attention — round-1 MFMA version (proven: fell out of top-5).
// S^T = mfma(K,Q); in-register softmax via shfl_xor; O = mfma(P, V^T).
// LDS: qS/kS 2x[64][40] u16 | vT 2x[64][72] u16 | posL [64][50] f32;
// pS aliases qS+kS after a barrier. Total 51.7 KB -> 3 blocks/CU.
// grid (8, 4, 64), block 256.
// ---------------------------------------------------------------------------
__global__ __launch_bounds__(256) void attn_kernel(
    const bf16*  __restrict__ Q,       // [64][784][64] NHWC (hk = hh*16+kc)
    const bf16*  __restrict__ KV,      // [64][784][384] NHWC
    const float* __restrict__ pos,     // [4][49][49]
    bf16* __restrict__ O)              // [64][784][256] NHWC (c = hh*64+d)
{
    int wjp = blockIdx.x & 1, wi = blockIdx.x >> 1;
    int hh  = blockIdx.y, n = blockIdx.z;
    int tid = threadIdx.x;
    int pbase = wi * 7 * 28 + wjp * 14;

    __shared__ __align__(16) char smem[51712];
    unsigned short* qS = (unsigned short*)smem;              // [2][64][40]
    unsigned short* kS = qS + 2 * 64 * 40;                   // [2][64][40]
    unsigned short* pS = (unsigned short*)smem;              // alias: [2][64][72]
    unsigned short* vT = (unsigned short*)(smem + 20480);    // [2][64][72]
    float*          posL = (float*)(smem + 20480 + 18432);   // [64][50]

    const unsigned short* Qu  = (const unsigned short*)Q;
    const unsigned short* KVu = (const unsigned short*)KV;

    // ---- stage q/k: 2 bufs x 2 windows x 64 rows x 5 halves (zero-padded) ----
    for (int idx = tid; idx < 1280; idx += 256) {
        int which = idx >= 640 ? 1 : 0;
        int t2 = idx - which * 640;
        int w = t2 / 320, rm = t2 - w * 320;
        int row = rm / 5, half = rm - row * 5;
        uint4 v = make_uint4(0u, 0u, 0u, 0u);
        if (row < 49 && half < 2) {
            int p = pbase + (row / 7) * 28 + w * 7 + (row % 7);
            const unsigned short* src = which
                ? &KVu[((size_t)n * PP + p) * 384 + hh * 96 + 16 + half * 8]
                : &Qu[((size_t)n * PP + p) * 64 + hh * 16 + half * 8];
            v = *(const uint4*)src;
        }
        *(uint4*)((which ? kS : qS) + (w * 64 + row) * 40 + half * 8) = v;
    }
    // ---- stage V transposed: vT[w][d][ki], zero rows for ki >= 49 ----
    for (int idx = tid; idx < 1024; idx += 256) {
        int w = idx >> 9, rm = idx & 511;
        int ki = rm >> 3, dq = rm & 7;
        union { uint4 q; unsigned short h[8]; } v;
        v.q = make_uint4(0u, 0u, 0u, 0u);
        if (ki < 49) {
            int p = pbase + (ki / 7) * 28 + w * 7 + (ki % 7);
            v.q = *(const uint4*)&KVu[((size_t)n * PP + p) * 384 + hh * 96 + 32 + dq * 8];
        }
#pragma unroll
        for (int j = 0; j < 8; j++)
            vT[(w * 64 + dq * 8 + j) * 72 + ki] = v.h[j];
    }
    // ---- stage pos [64][50], zero-padded ----
    for (int idx = tid; idx < 3200; idx += 256) {
        int r = idx / 50, c = idx - r * 50;
        posL[idx] = (r < 49 && c < 49) ? pos[((size_t)hh * 49 + r) * 49 + c] : 0.f;
    }
    __syncthreads();

    int wv = tid >> 6, ln = tid & 63, l15 = ln & 15, quad = ln >> 4;

    // ---- S^T via MFMA + in-register softmax; hold packed bf16 P ----
    uint2 pk[2][4];
#pragma unroll
    for (int w = 0; w < 2; w++) {
        short8 qf = *(const short8*)&qS[(w * 64 + wv * 16 + l15) * 40 + quad * 8];
        floatx4 a4[4];
#pragma unroll
        for (int kt = 0; kt < 4; kt++) {
            short8 kf = *(const short8*)&kS[(w * 64 + kt * 16 + l15) * 40 + quad * 8];
            a4[kt] = __builtin_amdgcn_mfma_f32_16x16x32_bf16(
                kf, qf, (floatx4){0.f, 0.f, 0.f, 0.f}, 0, 0, 0);
        }
        int q = wv * 16 + l15;
        float sv[16];
        float m = -1e30f;
#pragma unroll
        for (int kt = 0; kt < 4; kt++) {
#pragma unroll
            for (int r = 0; r < 4; r++) {
                int ki = kt * 16 + quad * 4 + r;
                float sc = (ki < 49)
                    ? a4[kt][r] * 0.25f + posL[q * 50 + ki]
                    : -1e30f;
                sv[kt * 4 + r] = sc;
                m = fmaxf(m, sc);
            }
        }
        m = fmaxf(m, __shfl_xor(m, 16));
        m = fmaxf(m, __shfl_xor(m, 32));
        float sum = 0.f;
#pragma unroll
        for (int i = 0; i < 16; i++) { sv[i] = __expf(sv[i] - m); sum += sv[i]; }
        sum += __shfl_xor(sum, 16);
        sum += __shfl_xor(sum, 32);
        float inv = 1.f / sum;
#pragma unroll
        for (int kt = 0; kt < 4; kt++) {
            union { uint2 u; unsigned short h[4]; } pku;
#pragma unroll
            for (int r = 0; r < 4; r++) pku.h[r] = f2bits(sv[kt * 4 + r] * inv);
            pk[w][kt] = pku.u;
        }
    }
    __syncthreads();   // all qS/kS MFMA reads done before aliasing writes

    {
        int q = wv * 16 + l15;
#pragma unroll
        for (int w = 0; w < 2; w++)
#pragma unroll
            for (int kt = 0; kt < 4; kt++)
                *(uint2*)&pS[(w * 64 + q) * 72 + kt * 16 + quad * 4] = pk[w][kt];
    }
    __syncthreads();

    // ---- O = relu(P @ V) via MFMA ----
    unsigned short* Ou = (unsigned short*)O;
#pragma unroll
    for (int w = 0; w < 2; w++) {
        short8 af0 = *(const short8*)&pS[(w * 64 + wv * 16 + l15) * 72 + quad * 8];
        short8 af1 = *(const short8*)&pS[(w * 64 + wv * 16 + l15) * 72 + 32 + quad * 8];
#pragma unroll
        for (int dt = 0; dt < 4; dt++) {
            floatx4 oacc = (floatx4){0.f, 0.f, 0.f, 0.f};
            short8 vf0 = *(const short8*)&vT[(w * 64 + dt * 16 + l15) * 72 + quad * 8];
            short8 vf1 = *(const short8*)&vT[(w * 64 + dt * 16 + l15) * 72 + 32 + quad * 8];
            oacc = __builtin_amdgcn_mfma_f32_16x16x32_bf16(af0, vf0, oacc, 0, 0, 0);
            oacc = __builtin_amdgcn_mfma_f32_16x16x32_bf16(af1, vf1, oacc, 0, 0, 0);
#pragma unroll
            for (int r = 0; r < 4; r++) {
                int q = wv * 16 + quad * 4 + r;
                if (q < 49) {
                    int p = pbase + (q / 7) * 28 + w * 7 + (q % 7);
                    Ou[((size_t)n * PP + p) * 256 + hh * 64 + dt * 16 + l15] =
                        f2bits(fmaxf(oacc[r], 0.f));
                }
            }
        }
    }
}

// ---------------------------------------------------------------------------
extern "C" void kernel_launch(void* const* d_in, const int* in_sizes, int n_in,
                              void* d_out, int out_size, void* d_ws, size_t ws_size,
                              hipStream_t stream)
{
    const float* x0     = (const float*)d_in[0];
    const float* dw0_w  = (const float*)d_in[1];
    const float* dw0_s  = (const float*)d_in[2];
    const float* dw0_b  = (const float*)d_in[3];
    const float* dw1_w  = (const float*)d_in[4];
    const float* dw1_s  = (const float*)d_in[5];
    const float* dw1_b  = (const float*)d_in[6];
    const float* f0w1   = (const float*)d_in[7];
    const float* f0s1   = (const float*)d_in[8];
    const float* f0b1   = (const float*)d_in[9];
    const float* f0w2   = (const float*)d_in[10];
    const float* f0s2   = (const float*)d_in[11];
    const float* f0b2   = (const float*)d_in[12];
    const float* f1w1   = (const float*)d_in[13];
    const float* f1s1   = (const float*)d_in[14];
    const float* f1b1   = (const float*)d_in[15];
    const float* f1w2   = (const float*)d_in[16];
    const float* f1s2   = (const float*)d_in[17];
    const float* f1b2   = (const float*)d_in[18];
    const float* qkv_w  = (const float*)d_in[19];
    const float* qkv_s  = (const float*)d_in[20];
    const float* qkv_b  = (const float*)d_in[21];
    const float* dws_w  = (const float*)d_in[22];
    const float* dws_s  = (const float*)d_in[23];
    const float* dws_b  = (const float*)d_in[24];
    const float* proj_w = (const float*)d_in[25];
    const float* proj_s = (const float*)d_in[26];
    const float* proj_b = (const float*)d_in[27];
    const float* pos    = (const float*)d_in[28];

    // -------- workspace (aliased, same proven r8 scheme) --------
    const size_t NXB = (size_t)BB * DIMC * PP * 4;    // 51,380,224 B
    char* base  = (char*)d_ws;
    float* X1   = (float*)base;
    bf16*  Hb   = (bf16*)(base + NXB);
    bf16*  Qb   = Hb;                                  // alias, disjoint in time
    char*  C_   = base + 2 * NXB;
    bf16*  QKVb = (bf16*)C_;
    float* X2   = (float*)C_;                          // alias, disjoint in time
    bf16*  X1b  = (bf16*)(base + 3 * NXB);             // 25.7 MB
    bf16*  Wc   = (bf16*)(base + 3 * NXB + NXB / 2);
    bf16*  Ob   = (bf16*)d_out;
    float* outp = (float*)d_out;

    bf16* Wf0w1 = Wc;                  // [512][256]
    bf16* Wf0w2 = Wf0w1 + 131072;      // [256][512]
    bf16* Wf1w1 = Wf0w2 + 131072;      // [512][256]
    bf16* Wf1w2 = Wf1w1 + 131072;      // [256][512]
    bf16* Wqkv  = Wf1w2 + 131072;      // [384][256]
    bf16* Wproj = Wqkv + 98304;        // [256][256]

    dim3 blk(256);

    // 0) weights fp32 -> bf16 (single merged launch)
    cvt_all<<<2688, blk, 0, stream>>>(f0w1, Wf0w1, f0w2, Wf0w2,
                                      f1w1, Wf1w1, f1w2, Wf1w2,
                                      qkv_w, Wqkv, proj_w, Wproj);

    // 1) x = x + dw0(x); mirror to NHWC bf16
    dw3x3_kernel<<<dim3(BB, DIMC / CPB), blk, 0, stream>>>(x0, dw0_w, dw0_s, dw0_b, X1);
    tr_cvt<<<dim3(25, 8, BB), blk, 0, stream>>>(X1, X1b);

    // 2-3) ffn0 (second GEMM refreshes both X1 fp32 and X1b NHWC)
    gemm_mfma<true, false, 0><<<dim3(7, HIDC / 64, BB), blk, 0, stream>>>(
        Wf0w1, X1b, f0s1, f0b1, nullptr, nullptr, Hb, HIDC, DIMC);
    gemm_mfma<false, true, 2><<<dim3(7, DIMC / 64, BB), blk, 0, stream>>>(
        Wf0w2, Hb, f0s2, f0b2, X1, X1, X1b, DIMC, HIDC);

    // 4-7) attention
    gemm_mfma<false, false, 0><<<dim3(7, 384 / 64, BB), blk, 0, stream>>>(
        Wqkv, X1b, qkv_s, qkv_b, nullptr, nullptr, QKVb, 384, DIMC);
    dws5x5_nhwc<<<dim3(196, BB), blk, 0, stream>>>(QKVb, dws_w, dws_s, dws_b, Qb);
    attn_kernel<<<dim3(8, NHH, BB), blk, 0, stream>>>(Qb, QKVb, pos, Ob);
    gemm_mfma<false, true, 1><<<dim3(7, DIMC / 64, BB), blk, 0, stream>>>(
        Wproj, Ob, proj_s, proj_b, X1, X1, nullptr, DIMC, DIMC);

    // 8) x = x + dw1(x)  (QKVb dead -> X2); mirror to NHWC bf16 (reuse X1b)
    dw3x3_kernel<<<dim3(BB, DIMC / CPB), blk, 0, stream>>>(X1, dw1_w, dw1_s, dw1_b, X2);
    tr_cvt<<<dim3(25, 8, BB), blk, 0, stream>>>(X2, X1b);

    // 9-10) ffn1, final fp32 NCHW to d_out
    gemm_mfma<true, false, 0><<<dim3(7, HIDC / 64, BB), blk, 0, stream>>>(
        Wf1w1, X1b, f1s1, f1b1, nullptr, nullptr, Hb, HIDC, DIMC);
    gemm_mfma<false, true, 1><<<dim3(7, DIMC / 64, BB), blk, 0, stream>>>(
        Wf1w2, Hb, f1s2, f1b2, X2, outp, nullptr, DIMC, HIDC);
}

// Round 6
// 555.592 us; speedup vs baseline: 1.3861x; 1.0608x over previous
//
#include <hip/hip_runtime.h>
#include <hip/hip_bf16.h>
#include <math.h>

typedef __hip_bfloat16 bf16;
typedef __attribute__((ext_vector_type(8))) short short8;   // 8 x bf16 MFMA frag
typedef __attribute__((ext_vector_type(4))) float floatx4;  // 4 x f32 MFMA acc

// Problem constants: B=64, DIM=256, HID=512, NH=4, KD=16, D=64, 28x28, WH=7
#define BB    64
#define DIMC  256
#define HIDC  512
#define NHH   4
#define HH_   28
#define WW_   28
#define PP    784   // 28*28

__device__ __forceinline__ float toF(bf16 x) { return __bfloat162float(x); }
__device__ __forceinline__ unsigned short f2bits(float f) {
    union { bf16 h; unsigned short u; } cv; cv.h = __float2bfloat16(f); return cv.u;
}
__device__ __forceinline__ float bits2f(unsigned short u) {
    union { unsigned int u32; float f; } cv; cv.u32 = ((unsigned int)u) << 16; return cv.f;
}

// ---------------------------------------------------------------------------
// fp32 -> bf16 weight convert — single merged launch for all 6 weight arrays
// ---------------------------------------------------------------------------
__global__ __launch_bounds__(256) void cvt_all(
    const float* __restrict__ s0, bf16* __restrict__ d0,   // 131072
    const float* __restrict__ s1, bf16* __restrict__ d1,   // 131072
    const float* __restrict__ s2, bf16* __restrict__ d2,   // 131072
    const float* __restrict__ s3, bf16* __restrict__ d3,   // 131072
    const float* __restrict__ s4, bf16* __restrict__ d4,   // 98304
    const float* __restrict__ s5, bf16* __restrict__ d5)   // 65536
{
    int i = blockIdx.x * 256 + threadIdx.x;
    if (i < 131072)                d0[i]          = __float2bfloat16(s0[i]);
    else if (i < 262144)           d1[i - 131072] = __float2bfloat16(s1[i - 131072]);
    else if (i < 393216)           d2[i - 262144] = __float2bfloat16(s2[i - 262144]);
    else if (i < 524288)           d3[i - 393216] = __float2bfloat16(s3[i - 393216]);
    else if (i < 622592)           d4[i - 524288] = __float2bfloat16(s4[i - 524288]);
    else if (i < 688128)           d5[i - 622592] = __float2bfloat16(s5[i - 622592]);
}

// ---------------------------------------------------------------------------
// fp32 NCHW [64][256][784] -> bf16 NHWC [64][784][256] (LDS 32x32 transpose)
// grid (25, 8, 64), block 256
// ---------------------------------------------------------------------------
__global__ __launch_bounds__(256) void tr_cvt(
    const float* __restrict__ in, bf16* __restrict__ out)
{
    __shared__ float t[32][33];
    int n  = blockIdx.z;
    int p0 = blockIdx.x * 32;
    int c0 = blockIdx.y * 32;
    int tx = threadIdx.x & 31;
    int ty = threadIdx.x >> 5;   // 0..7
#pragma unroll
    for (int e = 0; e < 4; e++) {
        int c = c0 + ty + e * 8;
        int p = p0 + tx;
        if (p < PP) t[ty + e * 8][tx] = in[((size_t)n * DIMC + c) * PP + p];
    }
    __syncthreads();
#pragma unroll
    for (int e = 0; e < 4; e++) {
        int p = p0 + ty + e * 8;
        int c = c0 + tx;
        if (p < PP) out[((size_t)n * PP + p) * DIMC + c] = __float2bfloat16(t[tx][ty + e * 8]);
    }
}

// ---------------------------------------------------------------------------
// Depthwise 3x3 conv + BN + residual (NCHW fp32) — round-0 LDS version.
// ---------------------------------------------------------------------------
#define CPB 4
__global__ __launch_bounds__(256) void dw3x3_kernel(
    const float* __restrict__ in, const float* __restrict__ w,
    const float* __restrict__ s, const float* __restrict__ b,
    float* __restrict__ out)
{
    __shared__ float t[CPB][30 * 30];        // padded planes, zero halo
    __shared__ float wS[CPB * 9 + 2 * CPB];  // 9 weights + scale + bias per ch

    int n   = blockIdx.x;
    int c0  = blockIdx.y * CPB;
    int tid = threadIdx.x;
    const float* ip = in  + ((size_t)n * DIMC + c0) * PP;
    float*       op = out + ((size_t)n * DIMC + c0) * PP;

    // weights/scale/bias -> LDS
    if (tid < CPB * 9)                wS[tid] = w[c0 * 9 + tid];
    else if (tid < CPB * 10)          wS[tid] = s[c0 + tid - CPB * 9];
    else if (tid < CPB * 11)          wS[tid] = b[c0 + tid - CPB * 10];

    // zero-fill padded planes (halo must be 0; interior overwritten below)
    for (int i = tid; i < CPB * 900; i += 256) ((float*)t)[i] = 0.f;
    __syncthreads();

    // stage: CPB*196 float4 tasks; each row of 28 = 7 aligned float4
    for (int idx = tid; idx < CPB * 196; idx += 256) {
        int ch  = idx / 196;
        int rm  = idx - ch * 196;
        int row = rm / 7, seg = rm - row * 7;
        float4 v = *(const float4*)&ip[ch * PP + row * 28 + seg * 4];
        float* dst = &t[ch][(row + 1) * 30 + seg * 4 + 1];
        dst[0] = v.x; dst[1] = v.y; dst[2] = v.z; dst[3] = v.w;
    }
    __syncthreads();

    // compute: 4-px segments; padded window rows row..row+2, cols x0..x0+5
    for (int idx = tid; idx < CPB * 196; idx += 256) {
        int ch  = idx / 196;
        int rm  = idx - ch * 196;
        int row = rm / 7, seg = rm - row * 7;
        int x0  = seg * 4;
        float w9[9];
#pragma unroll
        for (int i = 0; i < 9; i++) w9[i] = wS[ch * 9 + i];
        float sc = wS[CPB * 9 + ch], bb = wS[CPB * 10 + ch];

        float acc[4] = {0.f, 0.f, 0.f, 0.f};
        float ctr[4];
        const float* base = &t[ch][row * 30 + x0];
#pragma unroll
        for (int i = 0; i < 3; i++) {
            float r[6];
#pragma unroll
            for (int k = 0; k < 6; k++) r[k] = base[i * 30 + k];
            if (i == 1) { ctr[0] = r[1]; ctr[1] = r[2]; ctr[2] = r[3]; ctr[3] = r[4]; }
#pragma unroll
            for (int j = 0; j < 3; j++)
#pragma unroll
                for (int q = 0; q < 4; q++)
                    acc[q] += w9[i * 3 + j] * r[j + q];
        }
        float4 o;
        o.x = ctr[0] + acc[0] * sc + bb;
        o.y = ctr[1] + acc[1] * sc + bb;
        o.z = ctr[2] + acc[2] * sc + bb;
        o.w = ctr[3] + acc[3] * sc + bb;
        *(float4*)&op[ch * PP + row * 28 + x0] = o;
    }
}

// ---------------------------------------------------------------------------
// Per-head depthwise 5x5 + BN on q channels — ROUND-5 LDS REWRITE (standalone).
// Old: 25 bounds-guarded strided global taps per output -> 70.8 MB FETCH
// (11x over-fetch), 59.7 us. New: block per (head, image); stage the head's
// 16 q-channels for the whole 28x28 image into a zero-padded [32][32][16]
// LDS tile (each input line fetched once per block); 25 unconditional LDS
// taps per output. Accumulation order identical (zero taps add exact 0).
// grid (NHH, BB), block 256, LDS 32 KB.
// ---------------------------------------------------------------------------
__global__ __launch_bounds__(256) void dws5x5_nhwc(
    const bf16* __restrict__ qkv,   // [64][784][384]
    const float* __restrict__ w,    // [64][25]  (hk-major)
    const float* __restrict__ s, const float* __restrict__ b,
    bf16* __restrict__ qout)        // [64][784][64]
{
    __shared__ __align__(16) unsigned short qin[32 * 32 * 16];  // [r][c][ch]
    int hh  = blockIdx.x;
    int n   = blockIdx.y;
    int tid = threadIdx.x;
    const unsigned short* KVu = (const unsigned short*)qkv;

    int kcw = tid & 15;
    int hk  = hh * 16 + kcw;
    float w25[25];
#pragma unroll
    for (int i = 0; i < 25; i++) w25[i] = w[hk * 25 + i];
    float csc = s[hk], cbb = b[hk];

    // zero-fill (halo must be 0), then stage interior
    for (int i = tid; i < 4096; i += 256)
        ((uint4*)qin)[i] = make_uint4(0u, 0u, 0u, 0u);
    __syncthreads();
    for (int idx = tid; idx < 1568; idx += 256) {
        int p = idx >> 1, half = idx & 1;
        int h = p / 28, x = p - h * 28;
        uint4 v = *(const uint4*)&KVu[((size_t)n * PP + p) * 384 + hh * 96 + half * 8];
        *(uint4*)&qin[((h + 2) * 32 + (x + 2)) * 16 + half * 8] = v;
    }
    __syncthreads();

    // compute: 784 px x 16 ch tasks; taps at LDS (h+i, x+j) == global (h+i-2, x+j-2)
    for (int idx = tid; idx < 12544; idx += 256) {
        int p = idx >> 4;            // channel == kcw since 256 % 16 == 0
        int h = p / 28, x = p - h * 28;
        float acc = 0.f;
#pragma unroll
        for (int i = 0; i < 5; i++)
#pragma unroll
            for (int j = 0; j < 5; j++)
                acc += w25[i * 5 + j] * bits2f(qin[((h + i) * 32 + (x + j)) * 16 + kcw]);
        qout[((size_t)n * PP + p) * 64 + hk] = __float2bfloat16(acc * csc + cbb);
    }
}

// ---------------------------------------------------------------------------
// 1x1 conv as bf16 MFMA GEMM — round-3 2-phase double-buffered pipeline.
// Tile 64(co) x 112(p), K-step 32, 4 waves; prefetch t+1 into regs during
// MFMA on LDS[t&1]. OUTMODE: 0 = bf16 NHWC; 1 = fp32 NCHW; 2 = both.
// grid (7, M/64, 64)
// ---------------------------------------------------------------------------
template <bool RELU, bool RES, int OUTMODE>
__global__ __launch_bounds__(256) void gemm_mfma(
    const bf16* __restrict__ Wb,    // [M][K] bf16
    const bf16* __restrict__ X,     // [64][784][K] bf16 NHWC
    const float* __restrict__ S, const float* __restrict__ Bb,
    const float* __restrict__ res,  // [64][M][784] fp32 NCHW (if RES)
    float* __restrict__ outF,       // fp32 NCHW (OUTMODE 1/2)
    bf16*  __restrict__ outB,       // bf16 NHWC (OUTMODE 0/2)
    int M, int K)
{
    int n    = blockIdx.z;
    int co0  = blockIdx.y * 64;
    int p0   = blockIdx.x * 112;
    int tid  = threadIdx.x;
    int wv   = tid >> 6;
    int ln   = tid & 63;
    int l15  = ln & 15;
    int quad = ln >> 4;

    __shared__ __align__(16) unsigned short Blds[2][112 * 40];  // dbuf, pitch 40

    floatx4 acc[7];
#pragma unroll
    for (int t = 0; t < 7; t++) acc[t] = (floatx4){0.f, 0.f, 0.f, 0.f};

    const bf16* Arow = Wb + (size_t)(co0 + wv * 16 + l15) * K + quad * 8;
    const unsigned short* Xb = (const unsigned short*)X + ((size_t)n * PP + p0) * K;

    int pp_a = tid >> 2, G_a = tid & 3;                 // pp_a in [0,64)
    int idx_b = tid + 256;
    int pp_b = idx_b >> 2, G_b = idx_b & 3;             // pp_b in [64,128), valid < 112
    bool has_b = idx_b < 448;

    const unsigned short* pa = Xb + (size_t)pp_a * K + G_a * 8;
    const unsigned short* pb = Xb + (size_t)pp_b * K + G_b * 8;

    // prologue: stage tile 0 into LDS[0]; A-frag 0 into regs
    {
        uint4 va = *(const uint4*)pa;
        *(uint4*)&Blds[0][pp_a * 40 + G_a * 8] = va;
        if (has_b) {
            uint4 vb = *(const uint4*)pb;
            *(uint4*)&Blds[0][pp_b * 40 + G_b * 8] = vb;
        }
    }
    short8 af = *(const short8*)Arow;
    __syncthreads();

    int NT = K >> 5;
    for (int t = 0; t < NT; t++) {
        int cur = t & 1;
        // ---- issue prefetch of tile t+1 (held in regs) ----
        uint4 nva = make_uint4(0u, 0u, 0u, 0u), nvb = make_uint4(0u, 0u, 0u, 0u);
        short8 naf = af;
        if (t + 1 < NT) {
            nva = *(const uint4*)(pa + (t + 1) * 32);
            if (has_b) nvb = *(const uint4*)(pb + (t + 1) * 32);
            naf = *(const short8*)(Arow + (t + 1) * 32);
        }
        // ---- compute on LDS[cur] (not blocked by the loads above) ----
#pragma unroll
        for (int tt = 0; tt < 7; tt++) {
            short8 bfrag = *(const short8*)&Blds[cur][(tt * 16 + l15) * 40 + quad * 8];
            acc[tt] = __builtin_amdgcn_mfma_f32_16x16x32_bf16(af, bfrag, acc[tt], 0, 0, 0);
        }
        if (t + 1 < NT) {
            __syncthreads();   // iter t-1 readers of LDS[cur^1] are done
            *(uint4*)&Blds[cur ^ 1][pp_a * 40 + G_a * 8] = nva;
            if (has_b) *(uint4*)&Blds[cur ^ 1][pp_b * 40 + G_b * 8] = nvb;
            af = naf;
            __syncthreads();   // LDS[cur^1] ready for iter t+1
        }
    }

    int cobase = co0 + wv * 16 + quad * 4;
    float s4[4], b4[4];
#pragma unroll
    for (int r = 0; r < 4; r++) { s4[r] = S[cobase + r]; b4[r] = Bb[cobase + r]; }

#pragma unroll
    for (int t = 0; t < 7; t++) {
        int p = p0 + t * 16 + l15;   // always < 784
        float y[4];
#pragma unroll
        for (int r = 0; r < 4; r++) {
            y[r] = acc[t][r] * s4[r] + b4[r];
            if (RELU) y[r] = fmaxf(y[r], 0.f);
            if (RES) y[r] += res[((size_t)n * M + cobase + r) * PP + p];
        }
        if (OUTMODE == 1 || OUTMODE == 2) {
#pragma unroll
            for (int r = 0; r < 4; r++)
                outF[((size_t)n * M + cobase + r) * PP + p] = y[r];
        }
        if (OUTMODE == 0 || OUTMODE == 2) {
            union { unsigned short h4[4]; uint2 u; } pk;
#pragma unroll
            for (int r = 0; r < 4; r++) pk.h4[r] = f2bits(y[r]);
            *(uint2*)((unsigned short*)outB + ((size_t)n * PP + p) * M + cobase) = pk.u;
        }
    }
}

// ---------------------------------------------------------------------------
// 7x7 window attention — round-1 MFMA version (harness-proven at 589 us;
// round-4 fusion attempt REVERTED: it depended on uninitialized LDS).
// S^T = mfma(K,Q); in-register softmax via shfl_xor; O = mfma(P, V^T).
// LDS: qS/kS 2x[64][40] u16 | vT 2x[64][72] u16 | posL [64][50] f32;
// pS aliases qS+kS after a barrier. Total 51.7 KB -> 3 blocks/CU.
// grid (8, 4, 64), block 256.
// ---------------------------------------------------------------------------
__global__ __launch_bounds__(256) void attn_kernel(
    const bf16*  __restrict__ Q,       // [64][784][64] NHWC (hk = hh*16+kc)
    const bf16*  __restrict__ KV,      // [64][784][384] NHWC
    const float* __restrict__ pos,     // [4][49][49]
    bf16* __restrict__ O)              // [64][784][256] NHWC (c = hh*64+d)
{
    int wjp = blockIdx.x & 1, wi = blockIdx.x >> 1;
    int hh  = blockIdx.y, n = blockIdx.z;
    int tid = threadIdx.x;
    int pbase = wi * 7 * 28 + wjp * 14;

    __shared__ __align__(16) char smem[51712];
    unsigned short* qS = (unsigned short*)smem;              // [2][64][40]
    unsigned short* kS = qS + 2 * 64 * 40;                   // [2][64][40]
    unsigned short* pS = (unsigned short*)smem;              // alias: [2][64][72]
    unsigned short* vT = (unsigned short*)(smem + 20480);    // [2][64][72]
    float*          posL = (float*)(smem + 20480 + 18432);   // [64][50]

    const unsigned short* Qu  = (const unsigned short*)Q;
    const unsigned short* KVu = (const unsigned short*)KV;

    // ---- load q, k: 2 bufs x 2 windows x 64 rows x 5 halves (zero-padded) ----
    for (int idx = tid; idx < 1280; idx += 256) {
        int which = idx >= 640 ? 1 : 0;
        int t2 = idx - which * 640;
        int w = t2 / 320, rm = t2 - w * 320;
        int row = rm / 5, half = rm - row * 5;
        uint4 v = make_uint4(0u, 0u, 0u, 0u);
        if (row < 49 && half < 2) {
            int p = pbase + (row / 7) * 28 + w * 7 + (row % 7);
            const unsigned short* src = which
                ? &KVu[((size_t)n * PP + p) * 384 + hh * 96 + 16 + half * 8]
                : &Qu[((size_t)n * PP + p) * 64 + hh * 16 + half * 8];
            v = *(const uint4*)src;
        }
        *(uint4*)((which ? kS : qS) + (w * 64 + row) * 40 + half * 8) = v;
    }
    // ---- stage V transposed: vT[w][d][ki], zero cols for ki >= 49 ----
    for (int idx = tid; idx < 1024; idx += 256) {
        int w = idx >> 9, rm = idx & 511;
        int ki = rm >> 3, dq = rm & 7;
        union { uint4 q; unsigned short h[8]; } v;
        v.q = make_uint4(0u, 0u, 0u, 0u);
        if (ki < 49) {
            int p = pbase + (ki / 7) * 28 + w * 7 + (ki % 7);
            v.q = *(const uint4*)&KVu[((size_t)n * PP + p) * 384 + hh * 96 + 32 + dq * 8];
        }
#pragma unroll
        for (int j = 0; j < 8; j++)
            vT[(w * 64 + dq * 8 + j) * 72 + ki] = v.h[j];
    }
    // ---- stage pos [64][50], zero-padded ----
    for (int idx = tid; idx < 3200; idx += 256) {
        int r = idx / 50, c = idx - r * 50;
        posL[idx] = (r < 49 && c < 49) ? pos[((size_t)hh * 49 + r) * 49 + c] : 0.f;
    }
    __syncthreads();

    int wv = tid >> 6, ln = tid & 63, l15 = ln & 15, quad = ln >> 4;

    // ---- S^T via MFMA + in-register softmax; hold packed bf16 P ----
    uint2 pk[2][4];
#pragma unroll
    for (int w = 0; w < 2; w++) {
        short8 qf = *(const short8*)&qS[(w * 64 + wv * 16 + l15) * 40 + quad * 8];
        floatx4 a4[4];
#pragma unroll
        for (int kt = 0; kt < 4; kt++) {
            short8 kf = *(const short8*)&kS[(w * 64 + kt * 16 + l15) * 40 + quad * 8];
            a4[kt] = __builtin_amdgcn_mfma_f32_16x16x32_bf16(
                kf, qf, (floatx4){0.f, 0.f, 0.f, 0.f}, 0, 0, 0);
        }
        int q = wv * 16 + l15;
        float sv[16];
        float m = -1e30f;
#pragma unroll
        for (int kt = 0; kt < 4; kt++) {
#pragma unroll
            for (int r = 0; r < 4; r++) {
                int ki = kt * 16 + quad * 4 + r;
                float sc = (ki < 49)
                    ? a4[kt][r] * 0.25f + posL[q * 50 + ki]
                    : -1e30f;
                sv[kt * 4 + r] = sc;
                m = fmaxf(m, sc);
            }
        }
        m = fmaxf(m, __shfl_xor(m, 16));
        m = fmaxf(m, __shfl_xor(m, 32));
        float sum = 0.f;
#pragma unroll
        for (int i = 0; i < 16; i++) { sv[i] = __expf(sv[i] - m); sum += sv[i]; }
        sum += __shfl_xor(sum, 16);
        sum += __shfl_xor(sum, 32);
        float inv = 1.f / sum;
#pragma unroll
        for (int kt = 0; kt < 4; kt++) {
            union { uint2 u; unsigned short h[4]; } pku;
#pragma unroll
            for (int r = 0; r < 4; r++) pku.h[r] = f2bits(sv[kt * 4 + r] * inv);
            pk[w][kt] = pku.u;
        }
    }
    __syncthreads();   // all qS/kS MFMA reads done before aliasing writes

    {
        int q = wv * 16 + l15;
#pragma unroll
        for (int w = 0; w < 2; w++)
#pragma unroll
            for (int kt = 0; kt < 4; kt++)
                *(uint2*)&pS[(w * 64 + q) * 72 + kt * 16 + quad * 4] = pk[w][kt];
    }
    __syncthreads();

    // ---- O = relu(P @ V) via MFMA ----
    unsigned short* Ou = (unsigned short*)O;
#pragma unroll
    for (int w = 0; w < 2; w++) {
        short8 af0 = *(const short8*)&pS[(w * 64 + wv * 16 + l15) * 72 + quad * 8];
        short8 af1 = *(const short8*)&pS[(w * 64 + wv * 16 + l15) * 72 + 32 + quad * 8];
#pragma unroll
        for (int dt = 0; dt < 4; dt++) {
            floatx4 oacc = (floatx4){0.f, 0.f, 0.f, 0.f};
            short8 vf0 = *(const short8*)&vT[(w * 64 + dt * 16 + l15) * 72 + quad * 8];
            short8 vf1 = *(const short8*)&vT[(w * 64 + dt * 16 + l15) * 72 + 32 + quad * 8];
            oacc = __builtin_amdgcn_mfma_f32_16x16x32_bf16(af0, vf0, oacc, 0, 0, 0);
            oacc = __builtin_amdgcn_mfma_f32_16x16x32_bf16(af1, vf1, oacc, 0, 0, 0);
#pragma unroll
            for (int r = 0; r < 4; r++) {
                int q = wv * 16 + quad * 4 + r;
                if (q < 49) {
                    int p = pbase + (q / 7) * 28 + w * 7 + (q % 7);
                    Ou[((size_t)n * PP + p) * 256 + hh * 64 + dt * 16 + l15] =
                        f2bits(fmaxf(oacc[r], 0.f));
                }
            }
        }
    }
}

// ---------------------------------------------------------------------------
extern "C" void kernel_launch(void* const* d_in, const int* in_sizes, int n_in,
                              void* d_out, int out_size, void* d_ws, size_t ws_size,
                              hipStream_t stream)
{
    const float* x0     = (const float*)d_in[0];
    const float* dw0_w  = (const float*)d_in[1];
    const float* dw0_s  = (const float*)d_in[2];
    const float* dw0_b  = (const float*)d_in[3];
    const float* dw1_w  = (const float*)d_in[4];
    const float* dw1_s  = (const float*)d_in[5];
    const float* dw1_b  = (const float*)d_in[6];
    const float* f0w1   = (const float*)d_in[7];
    const float* f0s1   = (const float*)d_in[8];
    const float* f0b1   = (const float*)d_in[9];
    const float* f0w2   = (const float*)d_in[10];
    const float* f0s2   = (const float*)d_in[11];
    const float* f0b2   = (const float*)d_in[12];
    const float* f1w1   = (const float*)d_in[13];
    const float* f1s1   = (const float*)d_in[14];
    const float* f1b1   = (const float*)d_in[15];
    const float* f1w2   = (const float*)d_in[16];
    const float* f1s2   = (const float*)d_in[17];
    const float* f1b2   = (const float*)d_in[18];
    const float* qkv_w  = (const float*)d_in[19];
    const float* qkv_s  = (const float*)d_in[20];
    const float* qkv_b  = (const float*)d_in[21];
    const float* dws_w  = (const float*)d_in[22];
    const float* dws_s  = (const float*)d_in[23];
    const float* dws_b  = (const float*)d_in[24];
    const float* proj_w = (const float*)d_in[25];
    const float* proj_s = (const float*)d_in[26];
    const float* proj_b = (const float*)d_in[27];
    const float* pos    = (const float*)d_in[28];

    // -------- workspace (aliased, same proven r8 scheme) --------
    const size_t NXB = (size_t)BB * DIMC * PP * 4;    // 51,380,224 B
    char* base  = (char*)d_ws;
    float* X1   = (float*)base;
    bf16*  Hb   = (bf16*)(base + NXB);
    bf16*  Qb   = Hb;                                  // alias, disjoint in time
    char*  C_   = base + 2 * NXB;
    bf16*  QKVb = (bf16*)C_;
    float* X2   = (float*)C_;                          // alias, disjoint in time
    bf16*  X1b  = (bf16*)(base + 3 * NXB);             // 25.7 MB
    bf16*  Wc   = (bf16*)(base + 3 * NXB + NXB / 2);
    bf16*  Ob   = (bf16*)d_out;
    float* outp = (float*)d_out;

    bf16* Wf0w1 = Wc;                  // [512][256]
    bf16* Wf0w2 = Wf0w1 + 131072;      // [256][512]
    bf16* Wf1w1 = Wf0w2 + 131072;      // [512][256]
    bf16* Wf1w2 = Wf1w1 + 131072;      // [256][512]
    bf16* Wqkv  = Wf1w2 + 131072;      // [384][256]
    bf16* Wproj = Wqkv + 98304;        // [256][256]

    dim3 blk(256);

    // 0) weights fp32 -> bf16 (single merged launch)
    cvt_all<<<2688, blk, 0, stream>>>(f0w1, Wf0w1, f0w2, Wf0w2,
                                      f1w1, Wf1w1, f1w2, Wf1w2,
                                      qkv_w, Wqkv, proj_w, Wproj);

    // 1) x = x + dw0(x); mirror to NHWC bf16
    dw3x3_kernel<<<dim3(BB, DIMC / CPB), blk, 0, stream>>>(x0, dw0_w, dw0_s, dw0_b, X1);
    tr_cvt<<<dim3(25, 8, BB), blk, 0, stream>>>(X1, X1b);

    // 2-3) ffn0 (second GEMM refreshes both X1 fp32 and X1b NHWC)
    gemm_mfma<true, false, 0><<<dim3(7, HIDC / 64, BB), blk, 0, stream>>>(
        Wf0w1, X1b, f0s1, f0b1, nullptr, nullptr, Hb, HIDC, DIMC);
    gemm_mfma<false, true, 2><<<dim3(7, DIMC / 64, BB), blk, 0, stream>>>(
        Wf0w2, Hb, f0s2, f0b2, X1, X1, X1b, DIMC, HIDC);

    // 4-7) attention
    gemm_mfma<false, false, 0><<<dim3(7, 384 / 64, BB), blk, 0, stream>>>(
        Wqkv, X1b, qkv_s, qkv_b, nullptr, nullptr, QKVb, 384, DIMC);
    dws5x5_nhwc<<<dim3(NHH, BB), blk, 0, stream>>>(QKVb, dws_w, dws_s, dws_b, Qb);
    attn_kernel<<<dim3(8, NHH, BB), blk, 0, stream>>>(Qb, QKVb, pos, Ob);
    gemm_mfma<false, true, 1><<<dim3(7, DIMC / 64, BB), blk, 0, stream>>>(
        Wproj, Ob, proj_s, proj_b, X1, X1, nullptr, DIMC, DIMC);

    // 8) x = x + dw1(x)  (QKVb dead -> X2); mirror to NHWC bf16 (reuse X1b)
    dw3x3_kernel<<<dim3(BB, DIMC / CPB), blk, 0, stream>>>(X1, dw1_w, dw1_s, dw1_b, X2);
    tr_cvt<<<dim3(25, 8, BB), blk, 0, stream>>>(X2, X1b);

    // 9-10) ffn1, final fp32 NCHW to d_out
    gemm_mfma<true, false, 0><<<dim3(7, HIDC / 64, BB), blk, 0, stream>>>(
        Wf1w1, X1b, f1s1, f1b1, nullptr, nullptr, Hb, HIDC, DIMC);
    gemm_mfma<false, true, 1><<<dim3(7, DIMC / 64, BB), blk, 0, stream>>>(
        Wf1w2, Hb, f1s2, f1b2, X2, outp, nullptr, DIMC, HIDC);
}